// Round 1
// 362.395 us; speedup vs baseline: 1.2871x; 1.2871x over previous
//
#include <hip/hip_runtime.h>

#define S 2048
#define D 2048
#define H 16
#define HD 128
#define N3 6144  // 3*D

typedef __attribute__((ext_vector_type(8))) _Float16 f16x8;
typedef __attribute__((ext_vector_type(4))) float f32x4;
typedef unsigned short ushort_t;
typedef unsigned int uint_t;

// ---------------------------------------------------------------------------
// f16 helpers (v_cvt_f16_f32 is RNE)
// ---------------------------------------------------------------------------
__device__ __forceinline__ ushort_t f16_rne(float f) {
    _Float16 h = (_Float16)f;
    return __builtin_bit_cast(ushort_t, h);
}
__device__ __forceinline__ float f16_f32(ushort_t u) {
    return (float)__builtin_bit_cast(_Float16, u);
}

// f32 row-major -> f16 (activations)
__global__ __launch_bounds__(256) void convert_f16_kernel(
    const float* __restrict__ in, ushort_t* __restrict__ hi)
{
    const int i = blockIdx.x * 256 + threadIdx.x;  // per float4
    float4 v = ((const float4*)in)[i];
    ((ushort4*)hi)[i] = make_ushort4(f16_rne(v.x), f16_rne(v.y),
                                     f16_rne(v.z), f16_rne(v.w));
}

// W [K][N] f32 -> Wt [N][K] f16 (transpose + convert), 32x32 tiles.
__global__ __launch_bounds__(256) void convert_t_kernel(
    const float* __restrict__ in, ushort_t* __restrict__ hi,
    int Kdim, int Ndim)
{
    __shared__ float tile[32][33];
    const int k0 = blockIdx.x * 32, n0 = blockIdx.y * 32;
    const int tx = threadIdx.x & 31, ty = threadIdx.x >> 5;  // ty 0..7
    #pragma unroll
    for (int r = 0; r < 4; r++)
        tile[ty + r * 8][tx] = in[(size_t)(k0 + ty + r * 8) * Ndim + n0 + tx];
    __syncthreads();
    const int n  = threadIdx.x >> 3;        // 0..31 local col
    const int kc = (threadIdx.x & 7) * 4;   // 0..28 local k chunk
    const float v0 = tile[kc + 0][n], v1 = tile[kc + 1][n];
    const float v2 = tile[kc + 2][n], v3 = tile[kc + 3][n];
    const size_t off = (size_t)(n0 + n) * Kdim + k0 + kc;
    *(ushort4*)&hi[off] = make_ushort4(f16_rne(v0), f16_rne(v1),
                                       f16_rne(v2), f16_rne(v3));
}

// ---------------------------------------------------------------------------
// async global->LDS, 16 B per lane, wave-uniform LDS base (HW adds lane*16).
// ---------------------------------------------------------------------------
__device__ __forceinline__ void gload16(const ushort_t* g, ushort_t* l) {
    __builtin_amdgcn_global_load_lds(
        (const __attribute__((address_space(1))) unsigned int*)g,
        (__attribute__((address_space(3))) unsigned int*)l, 16, 0, 0);
}

// ---------------------------------------------------------------------------
// 1-term f16 GEMM core: C = A*B. BK=32, 16x16x32, dbuf 32 KB LDS.
// (R13: f16 single-term replaces bf16 hi/lo split — 11x11-bit mantissa
//  beats 8x15; halves MFMA work, cuts staging 3->2 streams.)
// ---------------------------------------------------------------------------
#define BK 32
#define TILE_ELEMS (128 * BK)

__device__ __forceinline__ void mm_core_1t(
    const ushort_t* __restrict__ Agh,
    const ushort_t* __restrict__ Bgh,
    const int K, ushort_t* lds, const int t, f32x4 (&acc)[4][4])
{
    const int lane = t & 63;
    const int wv   = t >> 6;
    const int lrow = lane >> 2;
    const int lk   = (lane & 3) * 8;
    const int quad = lane >> 4;
    const int lr   = lane & 15;
    const int wm   = (wv & 1) * 64;
    const int wn   = (wv >> 1) * 64;

    const int r0  = wv * 16;
    const int lo0 = r0 * BK;
    const int lo1 = (r0 + 64) * BK;

    auto stage = [&](int k0, int buf) {
        ushort_t* base = lds + buf * 2 * TILE_ELEMS;
        ushort_t* As_h = base;
        ushort_t* Bs_h = base + TILE_ELEMS;
        const size_t go0 = (size_t)(r0 + lrow) * K + k0 + lk;
        const size_t go1 = (size_t)(r0 + 64 + lrow) * K + k0 + lk;
        gload16(Agh + go0, As_h + lo0);
        gload16(Agh + go1, As_h + lo1);
        gload16(Bgh + go0, Bs_h + lo0);
        gload16(Bgh + go1, Bs_h + lo1);
    };

    stage(0, 0);

    const int niter = K / BK;
    for (int it = 0; it < niter; it++) {
        const int cur = it & 1;
        __syncthreads();  // drains vmcnt: tile it visible; buf cur^1 free

        if (it + 1 < niter) stage((it + 1) * BK, cur ^ 1);

        ushort_t* base = lds + cur * 2 * TILE_ELEMS;
        ushort_t* As_h = base;
        ushort_t* Bs_h = base + TILE_ELEMS;

        f16x8 af[4], bf[4];
        #pragma unroll
        for (int i = 0; i < 4; i++) {
            af[i] = *(const f16x8*)&As_h[(wm + i * 16 + lr) * BK + quad * 8];
            bf[i] = *(const f16x8*)&Bs_h[(wn + i * 16 + lr) * BK + quad * 8];
        }
        #pragma unroll
        for (int mt = 0; mt < 4; mt++)
            #pragma unroll
            for (int nt = 0; nt < 4; nt++)
                acc[mt][nt] = __builtin_amdgcn_mfma_f32_16x16x32_f16(
                    af[mt], bf[nt], acc[mt][nt], 0, 0, 0);
    }
}

// ---------------------------------------------------------------------------
// QKV GEMM (f16 1-term). q/k/v all stored f16.
// ---------------------------------------------------------------------------
__global__ __launch_bounds__(256) void gemm_qkv_mfma(
    const ushort_t* __restrict__ xh,
    const ushort_t* __restrict__ Wth,
    const float* __restrict__ bias, const float* __restrict__ freqs,
    const int* __restrict__ input_pos,
    ushort_t* __restrict__ qhg, ushort_t* __restrict__ khg,
    ushort_t* __restrict__ vhg)
{
    __shared__ ushort_t lds[2 * 2 * TILE_ELEMS];   // 32 KB
    const int t = threadIdx.x;
    const int col0 = blockIdx.x * 128;
    const int row0 = blockIdx.y * 128;

    f32x4 acc[4][4] = {};
    mm_core_1t(xh + (size_t)row0 * D,
               Wth + (size_t)col0 * D,
               D, lds, t, acc);

    const int lane = t & 63;
    const int quad = lane >> 4;
    const int lr   = lane & 15;
    const int wm = ((t >> 6) & 1) * 64;
    const int wn = ((t >> 6) >> 1) * 64;

    const int which = col0 >> 11;           // 0=q 1=k 2=v
    const int hh = (col0 & 2047) >> 7;

    if (which == 2) {
        ushort_t* vh_b = vhg + (size_t)hh * HD * S;
        #pragma unroll
        for (int nt = 0; nt < 4; nt++) {
            const int d = wn + nt * 16 + lr;
            const float bsc = bias[col0 + d];
            #pragma unroll
            for (int mt = 0; mt < 4; mt++) {
                #pragma unroll
                for (int reg = 0; reg < 4; reg++) {
                    const int m = row0 + wm + mt * 16 + quad * 4 + reg;
                    const float v = acc[mt][nt][reg] + bsc;
                    const int pos = input_pos[m];
                    vh_b[(size_t)d * S + pos] = f16_rne(v);
                }
            }
        }
    } else {
        ushort_t* oh_b = ((which == 0) ? qhg : khg) + (size_t)hh * S * HD;
        #pragma unroll
        for (int nt = 0; nt < 4; nt++) {
            const int d = wn + nt * 16 + lr;
            const float bsc = bias[col0 + d];
            #pragma unroll
            for (int mt = 0; mt < 4; mt++) {
                #pragma unroll
                for (int reg = 0; reg < 4; reg++) {
                    const int m = row0 + wm + mt * 16 + quad * 4 + reg;
                    const float v = acc[mt][nt][reg] + bsc;
                    const float* fc = &freqs[((size_t)m * 64 + (d >> 1)) * 2];
                    const float c = fc[0], s = fc[1];
                    const float p = __shfl_xor(v, 1);
                    const float o = (d & 1) ? (v * c + p * s) : (v * c - p * s);
                    const ushort_t hv = f16_rne(o);
                    const int hp = __shfl_xor((int)hv, 1);
                    if (!(d & 1)) {
                        const int srow = (which == 0) ? m : input_pos[m];
                        *(uint_t*)&oh_b[(size_t)srow * HD + d] =
                            (uint_t)hv | ((uint_t)hp << 16);
                    }
                }
            }
        }
    }
}

// ---------------------------------------------------------------------------
// MFMA flash attention, SPLIT-K x2 (flash-decoding). 1024 blocks:
// bi -> h = (bi&7)+8*((bi>>3)&1) (XCD locality), half=(bi>>4)&1, qi=bi>>5,
// r = (h&8)? qi : 31-qi (pairwise CU balance). Partial (unnorm O, m, l) ->
// ws; exact online-softmax merge in attn_combine_kernel.
// R13: all-f16, PV 1-term (P rounding 2^-12 now, was the dominant error).
// LDS 36 KB.
// ---------------------------------------------------------------------------
__global__ __launch_bounds__(256, 2) void attn_mfma_kernel(
    const ushort_t* __restrict__ qhg, const ushort_t* __restrict__ khg,
    const ushort_t* __restrict__ vhg,
    float* __restrict__ Opart, float* __restrict__ MLpart)
{
    __shared__ ushort_t Khs[2][4096];   // [buf][hf*512.. key*32 + d8] per wave chunk
    __shared__ ushort_t Vhs[2][4096];   // [buf][dim*32 + key8]
    __shared__ ushort_t Ps[64 * 32];

    const int bi   = blockIdx.x;           // 0..1023
    const int h    = (bi & 7) + 8 * ((bi >> 3) & 1);
    const int half = (bi >> 4) & 1;
    const int qi   = bi >> 5;              // 0..31
    const int r = (h & 8) ? qi : (31 - qi);
    const int q0 = r * 64;
    const int nhalf = r + 1;
    const int kt0 = half * nhalf;
    const int kt1 = kt0 + nhalf;
    const int t = threadIdx.x;
    const int w = t >> 6, lane = t & 63;
    const int lr = lane & 15, quad = lane >> 4;

    const size_t qrow = (size_t)h * S + q0 + w * 16 + lr;
    f16x8 qf[4];
    #pragma unroll
    for (int ks = 0; ks < 4; ks++)
        qf[ks] = *(const f16x8*)&qhg[qrow * HD + ks * 32 + quad * 8];

    const ushort_t* kh_b = khg + (size_t)h * S * HD;
    const ushort_t* vh_b = vhg + (size_t)h * HD * S;

    const int keyq = lane >> 2;   // 0..15
    const int sub  = lane & 3;    // 16B chunk index

    auto stage = [&](int kt, int buf) {
        const int k0 = kt * 32;
        #pragma unroll
        for (int hf = 0; hf < 2; hf++) {
            const size_t ksrc = (size_t)(k0 + hf * 16 + keyq) * HD + w * 32 + sub * 8;
            gload16(kh_b + ksrc, &Khs[buf][w * 1024 + hf * 512]);
            const int dim = w * 32 + hf * 16 + keyq;
            const size_t vsrc = (size_t)dim * S + k0 + sub * 8;
            gload16(vh_b + vsrc, &Vhs[buf][(w * 32 + hf * 16) * 32]);
        }
    };

    f32x4 O[8] = {};
    f32x4 Ol = {0.f, 0.f, 0.f, 0.f};   // ones-column: per-row denom (unnorm)
    float mrow[4];
    #pragma unroll
    for (int rr = 0; rr < 4; rr++) mrow[rr] = -1e30f;

    f16x8 onesv;
    #pragma unroll
    for (int i = 0; i < 8; i++) onesv[i] = (_Float16)1.0f;

    const float kSc = 0.08838834764831845f * 1.4426950408889634f; // scale*log2e

    stage(kt0, 0);

    for (int kt = kt0; kt < kt1; kt++) {
        const int k0 = kt * 32;
        const int cur = (kt - kt0) & 1;
        __syncthreads();  // drains vmcnt -> tile kt visible; buf cur^1 free

        if (kt + 1 < kt1) stage(kt + 1, cur ^ 1);

        // ---- scores (f16 q*k, f32 accum)
        f32x4 sa[2];
        #pragma unroll
        for (int nt = 0; nt < 2; nt++) {
            f32x4 s = {0.f, 0.f, 0.f, 0.f};
            #pragma unroll
            for (int ks = 0; ks < 4; ks++) {
                f16x8 kf = *(const f16x8*)&Khs[cur][ks * 1024 + (nt * 16 + lr) * 32 + quad * 8];
                s = __builtin_amdgcn_mfma_f32_16x16x32_f16(qf[ks], kf, s, 0, 0, 0);
            }
            sa[nt] = s;
        }

        const int rowbase = q0 + w * 16 + quad * 4;
        const bool need_mask = (k0 + 31) > (q0 + w * 16);
        float alpha[4], pv0[4], pv1[4];
        #pragma unroll
        for (int rr = 0; rr < 4; rr++) {
            float z0 = sa[0][rr] * kSc;
            float z1 = sa[1][rr] * kSc;
            if (need_mask) {
                const int rowg = rowbase + rr;
                if (k0 + lr > rowg)      z0 = -1e30f;
                if (k0 + 16 + lr > rowg) z1 = -1e30f;
            }
            float rm = fmaxf(z0, z1);
            #pragma unroll
            for (int off = 1; off < 16; off <<= 1)
                rm = fmaxf(rm, __shfl_xor(rm, off));
            const float nm = fmaxf(mrow[rr], rm);
            alpha[rr] = exp2f(mrow[rr] - nm);
            pv0[rr] = exp2f(z0 - nm);
            pv1[rr] = exp2f(z1 - nm);
            mrow[rr] = nm;
        }

        #pragma unroll
        for (int rr = 0; rr < 4; rr++) {
            const int prow = (w * 16 + quad * 4 + rr) * 32;
            Ps[prow + lr]      = f16_rne(pv0[rr]);
            Ps[prow + 16 + lr] = f16_rne(pv1[rr]);
        }
        // no barrier: each wave reads only its own P rows (lgkmcnt orders)

        #pragma unroll
        for (int nt = 0; nt < 8; nt++)
            #pragma unroll
            for (int rr = 0; rr < 4; rr++)
                O[nt][rr] *= alpha[rr];
        #pragma unroll
        for (int rr = 0; rr < 4; rr++)
            Ol[rr] *= alpha[rr];
        const f16x8 pf = *(const f16x8*)&Ps[(w * 16 + lr) * 32 + quad * 8];
        #pragma unroll
        for (int nt = 0; nt < 8; nt++) {
            f16x8 vf = *(const f16x8*)&Vhs[cur][(nt * 16 + lr) * 32 + quad * 8];
            O[nt] = __builtin_amdgcn_mfma_f32_16x16x32_f16(pf, vf, O[nt], 0, 0, 0);
        }
        Ol = __builtin_amdgcn_mfma_f32_16x16x32_f16(pf, onesv, Ol, 0, 0, 0);
    }

    // ---- store unnormalized partial O + (m, l) for the combine pass
    float* Ob = Opart + (size_t)bi * 64 * 128;
    #pragma unroll
    for (int rr = 0; rr < 4; rr++) {
        const int row = w * 16 + quad * 4 + rr;
        #pragma unroll
        for (int nt = 0; nt < 8; nt++)
            Ob[(size_t)row * 128 + nt * 16 + lr] = O[nt][rr];
        if (lr == 0) {
            MLpart[(size_t)bi * 128 + row * 2 + 0] = mrow[rr];
            MLpart[(size_t)bi * 128 + row * 2 + 1] = Ol[rr];
        }
    }
}

// ---------------------------------------------------------------------------
// Exact online-softmax merge of the two split-K halves -> ctxh (f16).
// ---------------------------------------------------------------------------
__global__ __launch_bounds__(128) void attn_combine_kernel(
    const float* __restrict__ Opart, const float* __restrict__ MLpart,
    ushort_t* __restrict__ ctxh)
{
    const int qt = blockIdx.x;   // 0..31 (qi in attn kernel)
    const int h  = blockIdx.y;   // 0..15
    const int t  = threadIdx.x;  // 0..127
    const int b0 = h | (qt << 5);          // half 0
    const int b1 = b0 | (1 << 4);          // half 1
    const int r = (h & 8) ? qt : (31 - qt);
    const int q0 = r * 64;

    __shared__ float sc[64][2];
    if (t < 64) {
        const float m0 = MLpart[(size_t)b0 * 128 + t * 2 + 0];
        const float l0 = MLpart[(size_t)b0 * 128 + t * 2 + 1];
        const float m1 = MLpart[(size_t)b1 * 128 + t * 2 + 0];
        const float l1 = MLpart[(size_t)b1 * 128 + t * 2 + 1];
        const float m = fmaxf(m0, m1);
        const float a0 = exp2f(m0 - m), a1 = exp2f(m1 - m);
        const float inv = 1.0f / (l0 * a0 + l1 * a1);
        sc[t][0] = a0 * inv;
        sc[t][1] = a1 * inv;
    }
    __syncthreads();

    const float* O0 = Opart + (size_t)b0 * 64 * 128;
    const float* O1 = Opart + (size_t)b1 * 64 * 128;
    for (int row = 0; row < 64; row++) {
        const float o = O0[(size_t)row * 128 + t] * sc[row][0] +
                        O1[(size_t)row * 128 + t] * sc[row][1];
        ctxh[(size_t)(q0 + row) * D + h * HD + t] = f16_rne(o);
    }
}

// ---------------------------------------------------------------------------
// Dense GEMM (f16 1-term): out = ctx @ Wd + b
// ---------------------------------------------------------------------------
__global__ __launch_bounds__(256) void gemm_dense_mfma(
    const ushort_t* __restrict__ Ah,
    const ushort_t* __restrict__ Wth,
    const float* __restrict__ bias, float* __restrict__ out)
{
    __shared__ ushort_t lds[2 * 2 * TILE_ELEMS];   // 32 KB
    const int t = threadIdx.x;
    const int col0 = blockIdx.x * 128;
    const int row0 = blockIdx.y * 128;

    f32x4 acc[4][4] = {};
    mm_core_1t(Ah + (size_t)row0 * D,
               Wth + (size_t)col0 * D,
               D, lds, t, acc);

    const int lane = t & 63;
    const int quad = lane >> 4;
    const int lr   = lane & 15;
    const int wm = ((t >> 6) & 1) * 64;
    const int wn = ((t >> 6) >> 1) * 64;

    #pragma unroll
    for (int nt = 0; nt < 4; nt++) {
        const int n = col0 + wn + nt * 16 + lr;
        const float bsc = bias[n];
        #pragma unroll
        for (int mt = 0; mt < 4; mt++) {
            #pragma unroll
            for (int reg = 0; reg < 4; reg++) {
                const int m = row0 + wm + mt * 16 + quad * 4 + reg;
                const float o = acc[mt][nt][reg] + bsc;
                const float po = __shfl_xor(o, 1);
                if (!(n & 1))
                    *(float2*)&out[(size_t)m * D + n] = make_float2(o, po);
            }
        }
    }
}

// ---------------------------------------------------------------------------
// Fallback f32 path (R2, known-good) for small workspace.
// ---------------------------------------------------------------------------
__global__ __launch_bounds__(256) void gemm_qkv_kernel(
    const float* __restrict__ x, const float* __restrict__ W,
    const float* __restrict__ bias, const float* __restrict__ freqs,
    const int* __restrict__ input_pos,
    float* __restrict__ qb, float* __restrict__ kb, float* __restrict__ vb)
{
    __shared__ float As[16][68];
    __shared__ float Bs[16][64];
    const int bx = blockIdx.x;
    const int by = blockIdx.y;
    const int tid = threadIdx.x;
    const int tx = tid & 15, ty = tid >> 4;
    const int row0 = by * 64, col0 = bx * 64;
    const int am = tid >> 2;
    const int ak = (tid & 3) * 4;
    const int bk = tid >> 4;
    const int bn = (tid & 15) * 4;
    float acc[4][4] = {};
    for (int k0 = 0; k0 < D; k0 += 16) {
        float4 av = *(const float4*)&x[(size_t)(row0 + am) * D + k0 + ak];
        float4 bv = *(const float4*)&W[(size_t)(k0 + bk) * N3 + col0 + bn];
        __syncthreads();
        As[ak + 0][am] = av.x; As[ak + 1][am] = av.y;
        As[ak + 2][am] = av.z; As[ak + 3][am] = av.w;
        *(float4*)&Bs[bk][bn] = bv;
        __syncthreads();
        #pragma unroll
        for (int k = 0; k < 16; k++) {
            float4 a4 = *(const float4*)&As[k][ty * 4];
            float4 b4 = *(const float4*)&Bs[k][tx * 4];
            float a[4] = {a4.x, a4.y, a4.z, a4.w};
            float b[4] = {b4.x, b4.y, b4.z, b4.w};
            #pragma unroll
            for (int r = 0; r < 4; r++)
                #pragma unroll
                for (int c = 0; c < 4; c++)
                    acc[r][c] += a[r] * b[c];
        }
    }
    const int j0 = col0 + tx * 4;
    const int which = j0 >> 11;
    const int hh = (j0 & 2047) >> 7;
    const int d0 = j0 & 127;
    const float bv0 = bias[j0 + 0], bv1 = bias[j0 + 1];
    const float bv2 = bias[j0 + 2], bv3 = bias[j0 + 3];
    #pragma unroll
    for (int r = 0; r < 4; r++) {
        const int grow = row0 + ty * 4 + r;
        float v0 = acc[r][0] + bv0, v1 = acc[r][1] + bv1;
        float v2 = acc[r][2] + bv2, v3 = acc[r][3] + bv3;
        if (which == 2) {
            const int pos = input_pos[grow];
            float4 o4 = make_float4(v0, v1, v2, v3);
            *(float4*)&vb[((size_t)hh * S + pos) * HD + d0] = o4;
        } else {
            const float* fc = &freqs[((size_t)grow * 64 + (d0 >> 1)) * 2];
            float c0 = fc[0], s0 = fc[1], c1 = fc[2], s1 = fc[3];
            float o0 = v0 * c0 - v1 * s0, o1 = v1 * c0 + v0 * s0;
            float o2 = v2 * c1 - v3 * s1, o3 = v3 * c1 + v2 * s1;
            float4 o4 = make_float4(o0, o1, o2, o3);
            if (which == 0) {
                *(float4*)&qb[((size_t)hh * S + grow) * HD + d0] = o4;
            } else {
                const int pos = input_pos[grow];
                *(float4*)&kb[((size_t)hh * S + pos) * HD + d0] = o4;
            }
        }
    }
}

#define BQ 64
#define ABK 32
#define QSTR 132
#define KVSTR 132
#define PSTR 68

__global__ __launch_bounds__(256) void attn_kernel(
    const float* __restrict__ qb, const float* __restrict__ kb,
    const float* __restrict__ vb, float* __restrict__ ctx)
{
    __shared__ float Qs[BQ * QSTR];
    __shared__ float KV[ABK * KVSTR];
    __shared__ float Psf[ABK * PSTR];

    const int pa = blockIdx.x;
    const int h  = blockIdx.y;
    const int t  = threadIdx.x;
    const int ty = t >> 4, tx = t & 15;
    const int i0  = ty * 4;
    const int j0  = tx * 2;
    const int dd0 = tx * 8;
    const int lr = t >> 3;
    const int lc = (t & 7) * 4;

    const float* kbase = kb + (size_t)h * S * HD;
    const float* vbase = vb + (size_t)h * S * HD;
    const float kSc = 0.08838834764831845f * 1.4426950408889634f;

    for (int ph = 0; ph < 2; ph++) {
        const int r = (ph == 0) ? pa : 31 - pa;
        const int q0 = r * BQ;
        const int ntiles = 2 * r + 2;

        #pragma unroll
        for (int pp = 0; pp < 2; pp++) {
            const int iq = lr + pp * 32;
            const float* src = qb + ((size_t)h * S + q0 + iq) * HD;
            #pragma unroll
            for (int ch = 0; ch < 4; ch++)
                *(float4*)&Qs[iq * QSTR + lc + ch * 32] =
                    *(const float4*)&src[lc + ch * 32];
        }

        float O[4][8] = {};
        float m[4], l[4];
        #pragma unroll
        for (int rr = 0; rr < 4; rr++) { m[rr] = -1e30f; l[rr] = 0.f; }

        float4 kpref[4];
        #pragma unroll
        for (int ch = 0; ch < 4; ch++)
            kpref[ch] = *(const float4*)&kbase[(size_t)lr * HD + lc + ch * 32];

        __syncthreads();

        for (int kt = 0; kt < ntiles; kt++) {
            const int k0 = kt * ABK;

            #pragma unroll
            for (int ch = 0; ch < 4; ch++)
                *(float4*)&KV[lr * KVSTR + lc + ch * 32] = kpref[ch];
            __syncthreads();

            float4 vpref[4];
            #pragma unroll
            for (int ch = 0; ch < 4; ch++)
                vpref[ch] = *(const float4*)&vbase[(size_t)(k0 + lr) * HD + lc + ch * 32];

            float acc[4][2] = {};
            #pragma unroll 4
            for (int d0 = 0; d0 < HD; d0 += 4) {
                float4 ka = *(const float4*)&KV[(j0 + 0) * KVSTR + d0];
                float4 kb4 = *(const float4*)&KV[(j0 + 1) * KVSTR + d0];
                #pragma unroll
                for (int rr = 0; rr < 4; rr++) {
                    float4 q4 = *(const float4*)&Qs[(i0 + rr) * QSTR + d0];
                    acc[rr][0] += q4.x * ka.x + q4.y * ka.y + q4.z * ka.z + q4.w * ka.w;
                    acc[rr][1] += q4.x * kb4.x + q4.y * kb4.y + q4.z * kb4.z + q4.w * kb4.w;
                }
            }

            const bool need_mask = (k0 + ABK - 1) > q0;
            float p[4][2], alpha[4];
            #pragma unroll
            for (int rr = 0; rr < 4; rr++) {
                float z0 = acc[rr][0] * kSc;
                float z1 = acc[rr][1] * kSc;
                if (need_mask) {
                    if (k0 + j0 + 0 > q0 + i0 + rr) z0 = -1e30f;
                    if (k0 + j0 + 1 > q0 + i0 + rr) z1 = -1e30f;
                }
                float rmax = fmaxf(z0, z1);
                #pragma unroll
                for (int off = 1; off < 16; off <<= 1)
                    rmax = fmaxf(rmax, __shfl_xor(rmax, off, 16));
                const float nm = fmaxf(m[rr], rmax);
                alpha[rr] = exp2f(m[rr] - nm);
                p[rr][0] = exp2f(z0 - nm);
                p[rr][1] = exp2f(z1 - nm);
                float ts = p[rr][0] + p[rr][1];
                #pragma unroll
                for (int off = 1; off < 16; off <<= 1)
                    ts += __shfl_xor(ts, off, 16);
                l[rr] = l[rr] * alpha[rr] + ts;
                m[rr] = nm;
            }
            __syncthreads();

            #pragma unroll
            for (int ch = 0; ch < 4; ch++)
                *(float4*)&KV[lr * KVSTR + lc + ch * 32] = vpref[ch];
            *(float4*)&Psf[(j0 + 0) * PSTR + i0] =
                make_float4(p[0][0], p[1][0], p[2][0], p[3][0]);
            *(float4*)&Psf[(j0 + 1) * PSTR + i0] =
                make_float4(p[0][1], p[1][1], p[2][1], p[3][1]);
            if (kt + 1 < ntiles) {
                #pragma unroll
                for (int ch = 0; ch < 4; ch++)
                    kpref[ch] = *(const float4*)&kbase[(size_t)(k0 + ABK + lr) * HD + lc + ch * 32];
            }
            __syncthreads();

            #pragma unroll
            for (int rr = 0; rr < 4; rr++)
                #pragma unroll
                for (int c = 0; c < 8; c++)
                    O[rr][c] *= alpha[rr];
            #pragma unroll 4
            for (int j = 0; j < ABK; j++) {
                float4 pj = *(const float4*)&Psf[j * PSTR + i0];
                float4 v0 = *(const float4*)&KV[j * KVSTR + dd0];
                float4 v1 = *(const float4*)&KV[j * KVSTR + dd0 + 4];
                const float pr[4] = {pj.x, pj.y, pj.z, pj.w};
                const float vv[8] = {v0.x, v0.y, v0.z, v0.w, v1.x, v1.y, v1.z, v1.w};
                #pragma unroll
                for (int rr = 0; rr < 4; rr++)
                    #pragma unroll
                    for (int c = 0; c < 8; c++)
                        O[rr][c] += pr[rr] * vv[c];
            }
            __syncthreads();
        }

        #pragma unroll
        for (int rr = 0; rr < 4; rr++) {
            const float inv = 1.0f / l[rr];
            const int qg = q0 + i0 + rr;
            float4 o0 = make_float4(O[rr][0] * inv, O[rr][1] * inv,
                                    O[rr][2] * inv, O[rr][3] * inv);
            float4 o1 = make_float4(O[rr][4] * inv, O[rr][5] * inv,
                                    O[rr][6] * inv, O[rr][7] * inv);
            float* dst = &ctx[((size_t)qg * H + h) * HD + dd0];
            *(float4*)&dst[0] = o0;
            *(float4*)&dst[4] = o1;
        }
        __syncthreads();
    }
}

__global__ __launch_bounds__(256) void gemm_dense_kernel(
    const float* __restrict__ A, const float* __restrict__ W,
    const float* __restrict__ bias, float* __restrict__ out)
{
    __shared__ float As[16][68];
    __shared__ float Bs[16][64];
    const int bx = blockIdx.x;
    const int by = blockIdx.y;
    const int tid = threadIdx.x;
    const int tx = tid & 15, ty = tid >> 4;
    const int row0 = by * 64, col0 = bx * 64;
    const int am = tid >> 2;
    const int ak = (tid & 3) * 4;
    const int bk = tid >> 4;
    const int bn = (tid & 15) * 4;
    float acc[4][4] = {};
    for (int k0 = 0; k0 < D; k0 += 16) {
        float4 av = *(const float4*)&A[(size_t)(row0 + am) * D + k0 + ak];
        float4 bv = *(const float4*)&W[(size_t)(k0 + bk) * D + col0 + bn];
        __syncthreads();
        As[ak + 0][am] = av.x; As[ak + 1][am] = av.y;
        As[ak + 2][am] = av.z; As[ak + 3][am] = av.w;
        *(float4*)&Bs[bk][bn] = bv;
        __syncthreads();
        #pragma unroll
        for (int k = 0; k < 16; k++) {
            float4 a4 = *(const float4*)&As[k][ty * 4];
            float4 b4 = *(const float4*)&Bs[k][tx * 4];
            float a[4] = {a4.x, a4.y, a4.z, a4.w};
            float b[4] = {b4.x, b4.y, b4.z, b4.w};
            #pragma unroll
            for (int r = 0; r < 4; r++)
                #pragma unroll
                for (int c = 0; c < 4; c++)
                    acc[r][c] += a[r] * b[c];
        }
    }
    const int j0 = col0 + tx * 4;
    const float bv0 = bias[j0 + 0], bv1 = bias[j0 + 1];
    const float bv2 = bias[j0 + 2], bv3 = bias[j0 + 3];
    #pragma unroll
    for (int r = 0; r < 4; r++) {
        const int grow = row0 + ty * 4 + r;
        float4 o4 = make_float4(acc[r][0] + bv0, acc[r][1] + bv1,
                                acc[r][2] + bv2, acc[r][3] + bv3);
        *(float4*)&out[(size_t)grow * D + j0] = o4;
    }
}

extern "C" void kernel_launch(void* const* d_in, const int* in_sizes, int n_in,
                              void* d_out, int out_size, void* d_ws, size_t ws_size,
                              hipStream_t stream) {
    const float* x      = (const float*)d_in[0];
    const float* freqs  = (const float*)d_in[1];
    const int*   pos    = (const int*)d_in[2];
    const float* Wqkv   = (const float*)d_in[3];
    const float* bqkv   = (const float*)d_in[4];
    const float* Wdense = (const float*)d_in[5];
    const float* bdense = (const float*)d_in[6];
    float* out = (float*)d_out;

    const size_t nSD = (size_t)S * D;   // 4 Mi elems
    const size_t nW1 = (size_t)D * N3;  // 12 Mi elems
    const size_t nOP = (size_t)1024 * 64 * 128;   // split-K partial O (f32)
    const size_t nML = (size_t)1024 * 128;        // split-K partial m,l (f32)

    const size_t needed =
        (6 * nSD + nW1) * sizeof(ushort_t) + (nOP + nML) * sizeof(float);

    if (ws_size >= needed) {
        ushort_t* qh   = (ushort_t*)d_ws;
        ushort_t* kh   = qh + nSD;
        ushort_t* vh   = kh + nSD;
        ushort_t* ctxh = vh + nSD;
        ushort_t* xh   = ctxh + nSD;
        ushort_t* Wth  = xh + nSD;
        ushort_t* Wdth = Wth + nW1;
        float* Opart = (float*)(Wdth + nSD);
        float* MLpart = Opart + nOP;

        convert_f16_kernel<<<nSD / 4 / 256, 256, 0, stream>>>(x, xh);
        dim3 gt1(D / 32, N3 / 32);
        convert_t_kernel<<<gt1, 256, 0, stream>>>(Wqkv, Wth, D, N3);
        dim3 gt2(D / 32, D / 32);
        convert_t_kernel<<<gt2, 256, 0, stream>>>(Wdense, Wdth, D, D);

        dim3 g1(N3 / 128, S / 128);
        gemm_qkv_mfma<<<g1, 256, 0, stream>>>(xh, Wth, bqkv, freqs,
                                              pos, qh, kh, vh);
        attn_mfma_kernel<<<1024, 256, 0, stream>>>(qh, kh, vh,
                                                   Opart, MLpart);
        dim3 gc(32, H);
        attn_combine_kernel<<<gc, 128, 0, stream>>>(Opart, MLpart, ctxh);
        dim3 g3(D / 128, S / 128);
        gemm_dense_mfma<<<g3, 256, 0, stream>>>(ctxh, Wdth, bdense, out);
    } else {
        // fallback: R2 f32 path (needs only 64 MiB)
        float* qb  = (float*)d_ws;
        float* kb  = qb + (size_t)H * S * HD;
        float* vb  = kb + (size_t)H * S * HD;
        float* ctx = vb + (size_t)H * S * HD;
        dim3 g1(N3 / 64, S / 64);
        gemm_qkv_kernel<<<g1, 256, 0, stream>>>(x, Wqkv, bqkv, freqs, pos, qb, kb, vb);
        dim3 g2(16, H);
        attn_kernel<<<g2, 256, 0, stream>>>(qb, kb, vb, ctx);
        dim3 g3(D / 64, S / 64);
        gemm_dense_kernel<<<g3, 256, 0, stream>>>(ctx, Wdense, bdense, out);
    }
}

// Round 2
// 354.773 us; speedup vs baseline: 1.3147x; 1.0215x over previous
//
#include <hip/hip_runtime.h>

#define S 2048
#define D 2048
#define H 16
#define HD 128
#define N3 6144  // 3*D

typedef __attribute__((ext_vector_type(8))) _Float16 f16x8;
typedef __attribute__((ext_vector_type(4))) float f32x4;
typedef unsigned short ushort_t;
typedef unsigned int uint_t;

// ---------------------------------------------------------------------------
// f16 helpers (v_cvt_f16_f32 is RNE)
// ---------------------------------------------------------------------------
__device__ __forceinline__ ushort_t f16_rne(float f) {
    _Float16 h = (_Float16)f;
    return __builtin_bit_cast(ushort_t, h);
}
__device__ __forceinline__ float f16_f32(ushort_t u) {
    return (float)__builtin_bit_cast(_Float16, u);
}

// f32 row-major -> f16 (activations)
__global__ __launch_bounds__(256) void convert_f16_kernel(
    const float* __restrict__ in, ushort_t* __restrict__ hi)
{
    const int i = blockIdx.x * 256 + threadIdx.x;  // per float4
    float4 v = ((const float4*)in)[i];
    ((ushort4*)hi)[i] = make_ushort4(f16_rne(v.x), f16_rne(v.y),
                                     f16_rne(v.z), f16_rne(v.w));
}

// W [K][N] f32 -> Wt [N][K] f16 (transpose + convert), 32x32 tiles.
__global__ __launch_bounds__(256) void convert_t_kernel(
    const float* __restrict__ in, ushort_t* __restrict__ hi,
    int Kdim, int Ndim)
{
    __shared__ float tile[32][33];
    const int k0 = blockIdx.x * 32, n0 = blockIdx.y * 32;
    const int tx = threadIdx.x & 31, ty = threadIdx.x >> 5;  // ty 0..7
    #pragma unroll
    for (int r = 0; r < 4; r++)
        tile[ty + r * 8][tx] = in[(size_t)(k0 + ty + r * 8) * Ndim + n0 + tx];
    __syncthreads();
    const int n  = threadIdx.x >> 3;        // 0..31 local col
    const int kc = (threadIdx.x & 7) * 4;   // 0..28 local k chunk
    const float v0 = tile[kc + 0][n], v1 = tile[kc + 1][n];
    const float v2 = tile[kc + 2][n], v3 = tile[kc + 3][n];
    const size_t off = (size_t)(n0 + n) * Kdim + k0 + kc;
    *(ushort4*)&hi[off] = make_ushort4(f16_rne(v0), f16_rne(v1),
                                       f16_rne(v2), f16_rne(v3));
}

// ---------------------------------------------------------------------------
// async global->LDS, 16 B per lane, wave-uniform LDS base (HW adds lane*16).
// ---------------------------------------------------------------------------
__device__ __forceinline__ void gload16(const ushort_t* g, ushort_t* l) {
    __builtin_amdgcn_global_load_lds(
        (const __attribute__((address_space(1))) unsigned int*)g,
        (__attribute__((address_space(3))) unsigned int*)l, 16, 0, 0);
}

__device__ __forceinline__ void vwait8() { asm volatile("s_waitcnt vmcnt(8)" ::: "memory"); }
__device__ __forceinline__ void vwait4() { asm volatile("s_waitcnt vmcnt(4)" ::: "memory"); }
__device__ __forceinline__ void vwait0() { asm volatile("s_waitcnt vmcnt(0)" ::: "memory"); }
__device__ __forceinline__ void lwait0() { asm volatile("s_waitcnt lgkmcnt(0)" ::: "memory"); }

// ---------------------------------------------------------------------------
// R14: QKV GEMM on the 256x256 / BK=64 / 8-wave / 8-phase counted-vmcnt
// schedule (T3+T4+T5). LDS 128 KB = 2 bufs x {A.k0,B.k0,A.k1,B.k1} regions
// (each 256 rows x 32 k, 16 KB). K-split regions -> 64 B row stride ->
// frag ds_read_b128 is bank-conflict-free, LDS stays LINEAR (gload_lds ok).
// Stage 1 half-region per phase, lead 6 halves; vmcnt(8) at end of odd
// phases guarantees the next even phase's regions; stage at phase p only
// overwrites regions last read at <= p-1 (verified per region kind).
// ---------------------------------------------------------------------------
#define QNT 32   // D / 64 K-tiles

__global__ __launch_bounds__(512, 2) void gemm_qkv_mfma(
    const ushort_t* __restrict__ xh,
    const ushort_t* __restrict__ Wth,
    const float* __restrict__ bias, const float* __restrict__ freqs,
    const int* __restrict__ input_pos,
    ushort_t* __restrict__ qhg, ushort_t* __restrict__ khg,
    ushort_t* __restrict__ vhg)
{
    __shared__ ushort_t lds[65536];   // 128 KB
    const int t = threadIdx.x;
    const int w = t >> 6, lane = t & 63;
    const int lr = lane & 15, quad = lane >> 4;
    const int wm = (w >> 2) * 128;    // 2 M-groups of waves
    const int wn = (w & 3) * 64;      // 4 N-groups

    const int col0 = blockIdx.x * 256;
    const int row0 = blockIdx.y * 256;
    const ushort_t* At = xh + (size_t)row0 * D;
    const ushort_t* Bt = Wth + (size_t)col0 * D;

    // staging addressing: wave w, load i covers region rows (i*8+w)*16..+15
    const int srow = lane >> 2;          // 0..15
    const int scol = (lane & 3) * 8;     // 0,8,16,24
    const size_t goff0 = (size_t)((0 * 8 + w) * 16 + srow) * D + scol;
    const size_t goff1 = (size_t)((1 * 8 + w) * 16 + srow) * D + scol;
    const int ldst0 = (0 * 8 + w) * 512;
    const int ldst1 = (1 * 8 + w) * 512;

    auto stage = [&](int j, int Tt) {
        const ushort_t* gb = (j & 1) ? Bt : At;
        const int off = Tt * 64 + (j >> 1) * 32;
        ushort_t* dst = lds + (Tt & 1) * 32768 + j * 8192;
        gload16(gb + goff0 + off, dst + ldst0);
        gload16(gb + goff1 + off, dst + ldst1);
    };

    f32x4 acc[8][4] = {};
    const int aro = (wm + lr) * 32 + quad * 8;
    const int bro = 8192 + (wn + lr) * 32 + quad * 8;

    // prologue: tile0 all 4 halves + tile1 k0 halves; wait tile0 complete
    stage(0, 0); stage(1, 0); stage(2, 0); stage(3, 0);
    stage(0, 1); stage(1, 1);
    vwait4();
    __builtin_amdgcn_sched_barrier(0);
    __builtin_amdgcn_s_barrier();

    f16x8 af[4], bf[4];

#define QPH(kk, mtg, RDB, DOSTAGE, SJ, ST, WAITN)                          \
    {                                                                      \
        const ushort_t* base = lds + (T & 1) * 32768 + (kk) * 16384;       \
        _Pragma("unroll")                                                  \
        for (int i = 0; i < 4; i++)                                        \
            af[i] = *(const f16x8*)&base[aro + ((mtg) * 4 + i) * 512];     \
        if (RDB) {                                                         \
            _Pragma("unroll")                                              \
            for (int n = 0; n < 4; n++)                                    \
                bf[n] = *(const f16x8*)&base[bro + n * 512];               \
        }                                                                  \
        if (DOSTAGE) stage(SJ, ST);                                        \
        __builtin_amdgcn_s_barrier();                                      \
        lwait0();                                                          \
        __builtin_amdgcn_sched_barrier(0);                                 \
        __builtin_amdgcn_s_setprio(1);                                     \
        _Pragma("unroll")                                                  \
        for (int i = 0; i < 4; i++)                                        \
            _Pragma("unroll")                                              \
            for (int n = 0; n < 4; n++)                                    \
                acc[(mtg) * 4 + i][n] =                                    \
                    __builtin_amdgcn_mfma_f32_16x16x32_f16(                \
                        af[i], bf[n], acc[(mtg) * 4 + i][n], 0, 0, 0);     \
        __builtin_amdgcn_s_setprio(0);                                     \
        WAITN;                                                             \
        __builtin_amdgcn_s_barrier();                                      \
    }

    for (int T = 0; T < QNT - 2; T++) {
        QPH(0, 0, true,  true, 2, T + 1, );
        QPH(0, 1, false, true, 3, T + 1, vwait8());
        QPH(1, 0, true,  true, 0, T + 2, );
        QPH(1, 1, false, true, 1, T + 2, vwait8());
    }
    {
        const int T = QNT - 2;
        QPH(0, 0, true,  true,  2, T + 1, );
        QPH(0, 1, false, true,  3, T + 1, vwait8());
        QPH(1, 0, true,  false, 0, 0, );
        QPH(1, 1, false, false, 0, 0, vwait4());
    }
    {
        const int T = QNT - 1;
        QPH(0, 0, true,  false, 0, 0, );
        QPH(0, 1, false, false, 0, 0, vwait0());
        QPH(1, 0, true,  false, 0, 0, );
        QPH(1, 1, false, false, 0, 0, );
    }
#undef QPH

    // ---- epilogue: bias + (RoPE for q/k | scatter for v)
    const int which = col0 >> 11;           // block-uniform (2048 % 256 == 0)
    if (which == 2) {
        #pragma unroll
        for (int nt = 0; nt < 4; nt++) {
            const int c = col0 + wn + nt * 16 + lr;
            const int hh = (c & 2047) >> 7;
            const int d = c & 127;
            ushort_t* vh_b = vhg + (size_t)hh * HD * S;
            const float bsc = bias[c];
            #pragma unroll
            for (int mt = 0; mt < 8; mt++) {
                #pragma unroll
                for (int reg = 0; reg < 4; reg++) {
                    const int m = row0 + wm + mt * 16 + quad * 4 + reg;
                    const float v = acc[mt][nt][reg] + bsc;
                    vh_b[(size_t)d * S + input_pos[m]] = f16_rne(v);
                }
            }
        }
    } else {
        ushort_t* ohg = (which == 0) ? qhg : khg;
        #pragma unroll
        for (int nt = 0; nt < 4; nt++) {
            const int c = col0 + wn + nt * 16 + lr;
            const int hh = (c & 2047) >> 7;
            const int d = c & 127;
            ushort_t* oh_b = ohg + (size_t)hh * S * HD;
            const float bsc = bias[c];
            #pragma unroll
            for (int mt = 0; mt < 8; mt++) {
                #pragma unroll
                for (int reg = 0; reg < 4; reg++) {
                    const int m = row0 + wm + mt * 16 + quad * 4 + reg;
                    const float v = acc[mt][nt][reg] + bsc;
                    const float* fc = &freqs[((size_t)m * 64 + (d >> 1)) * 2];
                    const float cc = fc[0], ss = fc[1];
                    const float p = __shfl_xor(v, 1);
                    const float o = (d & 1) ? (v * cc + p * ss) : (v * cc - p * ss);
                    const ushort_t hv = f16_rne(o);
                    const int hp = __shfl_xor((int)hv, 1);
                    if (!(d & 1)) {
                        const int srowg = (which == 0) ? m : input_pos[m];
                        *(uint_t*)&oh_b[(size_t)srowg * HD + d] =
                            (uint_t)hv | ((uint_t)hp << 16);
                    }
                }
            }
        }
    }
}

// ---------------------------------------------------------------------------
// 1-term f16 GEMM core (2-phase, 128x128): kept for the dense GEMM
// (N=2048 -> 256 blocks at 128^2 = full CU fill; 256^2 would be 64 blocks).
// ---------------------------------------------------------------------------
#define BK 32
#define TILE_ELEMS (128 * BK)

__device__ __forceinline__ void mm_core_1t(
    const ushort_t* __restrict__ Agh,
    const ushort_t* __restrict__ Bgh,
    const int K, ushort_t* lds, const int t, f32x4 (&acc)[4][4])
{
    const int lane = t & 63;
    const int wv   = t >> 6;
    const int lrow = lane >> 2;
    const int lk   = (lane & 3) * 8;
    const int quad = lane >> 4;
    const int lr   = lane & 15;
    const int wm   = (wv & 1) * 64;
    const int wn   = (wv >> 1) * 64;

    const int r0  = wv * 16;
    const int lo0 = r0 * BK;
    const int lo1 = (r0 + 64) * BK;

    auto stage = [&](int k0, int buf) {
        ushort_t* base = lds + buf * 2 * TILE_ELEMS;
        ushort_t* As_h = base;
        ushort_t* Bs_h = base + TILE_ELEMS;
        const size_t go0 = (size_t)(r0 + lrow) * K + k0 + lk;
        const size_t go1 = (size_t)(r0 + 64 + lrow) * K + k0 + lk;
        gload16(Agh + go0, As_h + lo0);
        gload16(Agh + go1, As_h + lo1);
        gload16(Bgh + go0, Bs_h + lo0);
        gload16(Bgh + go1, Bs_h + lo1);
    };

    stage(0, 0);

    const int niter = K / BK;
    for (int it = 0; it < niter; it++) {
        const int cur = it & 1;
        __syncthreads();  // drains vmcnt: tile it visible; buf cur^1 free

        if (it + 1 < niter) stage((it + 1) * BK, cur ^ 1);

        ushort_t* base = lds + cur * 2 * TILE_ELEMS;
        ushort_t* As_h = base;
        ushort_t* Bs_h = base + TILE_ELEMS;

        f16x8 af[4], bf[4];
        #pragma unroll
        for (int i = 0; i < 4; i++) {
            af[i] = *(const f16x8*)&As_h[(wm + i * 16 + lr) * BK + quad * 8];
            bf[i] = *(const f16x8*)&Bs_h[(wn + i * 16 + lr) * BK + quad * 8];
        }
        #pragma unroll
        for (int mt = 0; mt < 4; mt++)
            #pragma unroll
            for (int nt = 0; nt < 4; nt++)
                acc[mt][nt] = __builtin_amdgcn_mfma_f32_16x16x32_f16(
                    af[mt], bf[nt], acc[mt][nt], 0, 0, 0);
    }
}

// ---------------------------------------------------------------------------
// MFMA flash attention, SPLIT-K x2 (flash-decoding). 1024 blocks:
// bi -> h = (bi&7)+8*((bi>>3)&1) (XCD locality), half=(bi>>4)&1, qi=bi>>5,
// r = (h&8)? qi : 31-qi (pairwise CU balance). Partial (unnorm O, m, l) ->
// ws; exact online-softmax merge in attn_combine_kernel. All-f16, PV 1-term.
// ---------------------------------------------------------------------------
__global__ __launch_bounds__(256, 2) void attn_mfma_kernel(
    const ushort_t* __restrict__ qhg, const ushort_t* __restrict__ khg,
    const ushort_t* __restrict__ vhg,
    float* __restrict__ Opart, float* __restrict__ MLpart)
{
    __shared__ ushort_t Khs[2][4096];   // [buf][hf*512.. key*32 + d8] per wave chunk
    __shared__ ushort_t Vhs[2][4096];   // [buf][dim*32 + key8]
    __shared__ ushort_t Ps[64 * 32];

    const int bi   = blockIdx.x;           // 0..1023
    const int h    = (bi & 7) + 8 * ((bi >> 3) & 1);
    const int half = (bi >> 4) & 1;
    const int qi   = bi >> 5;              // 0..31
    const int r = (h & 8) ? qi : (31 - qi);
    const int q0 = r * 64;
    const int nhalf = r + 1;
    const int kt0 = half * nhalf;
    const int kt1 = kt0 + nhalf;
    const int t = threadIdx.x;
    const int w = t >> 6, lane = t & 63;
    const int lr = lane & 15, quad = lane >> 4;

    const size_t qrow = (size_t)h * S + q0 + w * 16 + lr;
    f16x8 qf[4];
    #pragma unroll
    for (int ks = 0; ks < 4; ks++)
        qf[ks] = *(const f16x8*)&qhg[qrow * HD + ks * 32 + quad * 8];

    const ushort_t* kh_b = khg + (size_t)h * S * HD;
    const ushort_t* vh_b = vhg + (size_t)h * HD * S;

    const int keyq = lane >> 2;   // 0..15
    const int sub  = lane & 3;    // 16B chunk index

    auto stage = [&](int kt, int buf) {
        const int k0 = kt * 32;
        #pragma unroll
        for (int hf = 0; hf < 2; hf++) {
            const size_t ksrc = (size_t)(k0 + hf * 16 + keyq) * HD + w * 32 + sub * 8;
            gload16(kh_b + ksrc, &Khs[buf][w * 1024 + hf * 512]);
            const int dim = w * 32 + hf * 16 + keyq;
            const size_t vsrc = (size_t)dim * S + k0 + sub * 8;
            gload16(vh_b + vsrc, &Vhs[buf][(w * 32 + hf * 16) * 32]);
        }
    };

    f32x4 O[8] = {};
    f32x4 Ol = {0.f, 0.f, 0.f, 0.f};   // ones-column: per-row denom (unnorm)
    float mrow[4];
    #pragma unroll
    for (int rr = 0; rr < 4; rr++) mrow[rr] = -1e30f;

    f16x8 onesv;
    #pragma unroll
    for (int i = 0; i < 8; i++) onesv[i] = (_Float16)1.0f;

    const float kSc = 0.08838834764831845f * 1.4426950408889634f; // scale*log2e

    stage(kt0, 0);

    for (int kt = kt0; kt < kt1; kt++) {
        const int k0 = kt * 32;
        const int cur = (kt - kt0) & 1;
        __syncthreads();  // drains vmcnt -> tile kt visible; buf cur^1 free

        if (kt + 1 < kt1) stage(kt + 1, cur ^ 1);

        // ---- scores (f16 q*k, f32 accum)
        f32x4 sa[2];
        #pragma unroll
        for (int nt = 0; nt < 2; nt++) {
            f32x4 s = {0.f, 0.f, 0.f, 0.f};
            #pragma unroll
            for (int ks = 0; ks < 4; ks++) {
                f16x8 kf = *(const f16x8*)&Khs[cur][ks * 1024 + (nt * 16 + lr) * 32 + quad * 8];
                s = __builtin_amdgcn_mfma_f32_16x16x32_f16(qf[ks], kf, s, 0, 0, 0);
            }
            sa[nt] = s;
        }

        const int rowbase = q0 + w * 16 + quad * 4;
        const bool need_mask = (k0 + 31) > (q0 + w * 16);
        float alpha[4], pv0[4], pv1[4];
        #pragma unroll
        for (int rr = 0; rr < 4; rr++) {
            float z0 = sa[0][rr] * kSc;
            float z1 = sa[1][rr] * kSc;
            if (need_mask) {
                const int rowg = rowbase + rr;
                if (k0 + lr > rowg)      z0 = -1e30f;
                if (k0 + 16 + lr > rowg) z1 = -1e30f;
            }
            float rm = fmaxf(z0, z1);
            #pragma unroll
            for (int off = 1; off < 16; off <<= 1)
                rm = fmaxf(rm, __shfl_xor(rm, off));
            const float nm = fmaxf(mrow[rr], rm);
            alpha[rr] = exp2f(mrow[rr] - nm);
            pv0[rr] = exp2f(z0 - nm);
            pv1[rr] = exp2f(z1 - nm);
            mrow[rr] = nm;
        }

        #pragma unroll
        for (int rr = 0; rr < 4; rr++) {
            const int prow = (w * 16 + quad * 4 + rr) * 32;
            Ps[prow + lr]      = f16_rne(pv0[rr]);
            Ps[prow + 16 + lr] = f16_rne(pv1[rr]);
        }
        // no barrier: each wave reads only its own P rows (lgkmcnt orders)

        #pragma unroll
        for (int nt = 0; nt < 8; nt++)
            #pragma unroll
            for (int rr = 0; rr < 4; rr++)
                O[nt][rr] *= alpha[rr];
        #pragma unroll
        for (int rr = 0; rr < 4; rr++)
            Ol[rr] *= alpha[rr];
        const f16x8 pf = *(const f16x8*)&Ps[(w * 16 + lr) * 32 + quad * 8];
        #pragma unroll
        for (int nt = 0; nt < 8; nt++) {
            f16x8 vf = *(const f16x8*)&Vhs[cur][(nt * 16 + lr) * 32 + quad * 8];
            O[nt] = __builtin_amdgcn_mfma_f32_16x16x32_f16(pf, vf, O[nt], 0, 0, 0);
        }
        Ol = __builtin_amdgcn_mfma_f32_16x16x32_f16(pf, onesv, Ol, 0, 0, 0);
    }

    // ---- store unnormalized partial O + (m, l) for the combine pass
    float* Ob = Opart + (size_t)bi * 64 * 128;
    #pragma unroll
    for (int rr = 0; rr < 4; rr++) {
        const int row = w * 16 + quad * 4 + rr;
        #pragma unroll
        for (int nt = 0; nt < 8; nt++)
            Ob[(size_t)row * 128 + nt * 16 + lr] = O[nt][rr];
        if (lr == 0) {
            MLpart[(size_t)bi * 128 + row * 2 + 0] = mrow[rr];
            MLpart[(size_t)bi * 128 + row * 2 + 1] = Ol[rr];
        }
    }
}

// ---------------------------------------------------------------------------
// Exact online-softmax merge of the two split-K halves -> ctxh (f16).
// ---------------------------------------------------------------------------
__global__ __launch_bounds__(128) void attn_combine_kernel(
    const float* __restrict__ Opart, const float* __restrict__ MLpart,
    ushort_t* __restrict__ ctxh)
{
    const int qt = blockIdx.x;   // 0..31 (qi in attn kernel)
    const int h  = blockIdx.y;   // 0..15
    const int t  = threadIdx.x;  // 0..127
    const int b0 = h | (qt << 5);          // half 0
    const int b1 = b0 | (1 << 4);          // half 1
    const int r = (h & 8) ? qt : (31 - qt);
    const int q0 = r * 64;

    __shared__ float sc[64][2];
    if (t < 64) {
        const float m0 = MLpart[(size_t)b0 * 128 + t * 2 + 0];
        const float l0 = MLpart[(size_t)b0 * 128 + t * 2 + 1];
        const float m1 = MLpart[(size_t)b1 * 128 + t * 2 + 0];
        const float l1 = MLpart[(size_t)b1 * 128 + t * 2 + 1];
        const float m = fmaxf(m0, m1);
        const float a0 = exp2f(m0 - m), a1 = exp2f(m1 - m);
        const float inv = 1.0f / (l0 * a0 + l1 * a1);
        sc[t][0] = a0 * inv;
        sc[t][1] = a1 * inv;
    }
    __syncthreads();

    const float* O0 = Opart + (size_t)b0 * 64 * 128;
    const float* O1 = Opart + (size_t)b1 * 64 * 128;
    for (int row = 0; row < 64; row++) {
        const float o = O0[(size_t)row * 128 + t] * sc[row][0] +
                        O1[(size_t)row * 128 + t] * sc[row][1];
        ctxh[(size_t)(q0 + row) * D + h * HD + t] = f16_rne(o);
    }
}

// ---------------------------------------------------------------------------
// Dense GEMM (f16 1-term): out = ctx @ Wd + b
// ---------------------------------------------------------------------------
__global__ __launch_bounds__(256) void gemm_dense_mfma(
    const ushort_t* __restrict__ Ah,
    const ushort_t* __restrict__ Wth,
    const float* __restrict__ bias, float* __restrict__ out)
{
    __shared__ ushort_t lds[2 * 2 * TILE_ELEMS];   // 32 KB
    const int t = threadIdx.x;
    const int col0 = blockIdx.x * 128;
    const int row0 = blockIdx.y * 128;

    f32x4 acc[4][4] = {};
    mm_core_1t(Ah + (size_t)row0 * D,
               Wth + (size_t)col0 * D,
               D, lds, t, acc);

    const int lane = t & 63;
    const int quad = lane >> 4;
    const int lr   = lane & 15;
    const int wm = ((t >> 6) & 1) * 64;
    const int wn = ((t >> 6) >> 1) * 64;

    #pragma unroll
    for (int nt = 0; nt < 4; nt++) {
        const int n = col0 + wn + nt * 16 + lr;
        const float bsc = bias[n];
        #pragma unroll
        for (int mt = 0; mt < 4; mt++) {
            #pragma unroll
            for (int reg = 0; reg < 4; reg++) {
                const int m = row0 + wm + mt * 16 + quad * 4 + reg;
                const float o = acc[mt][nt][reg] + bsc;
                const float po = __shfl_xor(o, 1);
                if (!(n & 1))
                    *(float2*)&out[(size_t)m * D + n] = make_float2(o, po);
            }
        }
    }
}

// ---------------------------------------------------------------------------
// Fallback f32 path (R2, known-good) for small workspace.
// ---------------------------------------------------------------------------
__global__ __launch_bounds__(256) void gemm_qkv_kernel(
    const float* __restrict__ x, const float* __restrict__ W,
    const float* __restrict__ bias, const float* __restrict__ freqs,
    const int* __restrict__ input_pos,
    float* __restrict__ qb, float* __restrict__ kb, float* __restrict__ vb)
{
    __shared__ float As[16][68];
    __shared__ float Bs[16][64];
    const int bx = blockIdx.x;
    const int by = blockIdx.y;
    const int tid = threadIdx.x;
    const int tx = tid & 15, ty = tid >> 4;
    const int row0 = by * 64, col0 = bx * 64;
    const int am = tid >> 2;
    const int ak = (tid & 3) * 4;
    const int bk = tid >> 4;
    const int bn = (tid & 15) * 4;
    float acc[4][4] = {};
    for (int k0 = 0; k0 < D; k0 += 16) {
        float4 av = *(const float4*)&x[(size_t)(row0 + am) * D + k0 + ak];
        float4 bv = *(const float4*)&W[(size_t)(k0 + bk) * N3 + col0 + bn];
        __syncthreads();
        As[ak + 0][am] = av.x; As[ak + 1][am] = av.y;
        As[ak + 2][am] = av.z; As[ak + 3][am] = av.w;
        *(float4*)&Bs[bk][bn] = bv;
        __syncthreads();
        #pragma unroll
        for (int k = 0; k < 16; k++) {
            float4 a4 = *(const float4*)&As[k][ty * 4];
            float4 b4 = *(const float4*)&Bs[k][tx * 4];
            float a[4] = {a4.x, a4.y, a4.z, a4.w};
            float b[4] = {b4.x, b4.y, b4.z, b4.w};
            #pragma unroll
            for (int r = 0; r < 4; r++)
                #pragma unroll
                for (int c = 0; c < 4; c++)
                    acc[r][c] += a[r] * b[c];
        }
    }
    const int j0 = col0 + tx * 4;
    const int which = j0 >> 11;
    const int hh = (j0 & 2047) >> 7;
    const int d0 = j0 & 127;
    const float bv0 = bias[j0 + 0], bv1 = bias[j0 + 1];
    const float bv2 = bias[j0 + 2], bv3 = bias[j0 + 3];
    #pragma unroll
    for (int r = 0; r < 4; r++) {
        const int grow = row0 + ty * 4 + r;
        float v0 = acc[r][0] + bv0, v1 = acc[r][1] + bv1;
        float v2 = acc[r][2] + bv2, v3 = acc[r][3] + bv3;
        if (which == 2) {
            const int pos = input_pos[grow];
            float4 o4 = make_float4(v0, v1, v2, v3);
            *(float4*)&vb[((size_t)hh * S + pos) * HD + d0] = o4;
        } else {
            const float* fc = &freqs[((size_t)grow * 64 + (d0 >> 1)) * 2];
            float c0 = fc[0], s0 = fc[1], c1 = fc[2], s1 = fc[3];
            float o0 = v0 * c0 - v1 * s0, o1 = v1 * c0 + v0 * s0;
            float o2 = v2 * c1 - v3 * s1, o3 = v3 * c1 + v2 * s1;
            float4 o4 = make_float4(o0, o1, o2, o3);
            if (which == 0) {
                *(float4*)&qb[((size_t)hh * S + grow) * HD + d0] = o4;
            } else {
                const int pos = input_pos[grow];
                *(float4*)&kb[((size_t)hh * S + pos) * HD + d0] = o4;
            }
        }
    }
}

#define BQ 64
#define ABK 32
#define QSTR 132
#define KVSTR 132
#define PSTR 68

__global__ __launch_bounds__(256) void attn_kernel(
    const float* __restrict__ qb, const float* __restrict__ kb,
    const float* __restrict__ vb, float* __restrict__ ctx)
{
    __shared__ float Qs[BQ * QSTR];
    __shared__ float KV[ABK * KVSTR];
    __shared__ float Psf[ABK * PSTR];

    const int pa = blockIdx.x;
    const int h  = blockIdx.y;
    const int t  = threadIdx.x;
    const int ty = t >> 4, tx = t & 15;
    const int i0  = ty * 4;
    const int j0  = tx * 2;
    const int dd0 = tx * 8;
    const int lr = t >> 3;
    const int lc = (t & 7) * 4;

    const float* kbase = kb + (size_t)h * S * HD;
    const float* vbase = vb + (size_t)h * S * HD;
    const float kSc = 0.08838834764831845f * 1.4426950408889634f;

    for (int ph = 0; ph < 2; ph++) {
        const int r = (ph == 0) ? pa : 31 - pa;
        const int q0 = r * BQ;
        const int ntiles = 2 * r + 2;

        #pragma unroll
        for (int pp = 0; pp < 2; pp++) {
            const int iq = lr + pp * 32;
            const float* src = qb + ((size_t)h * S + q0 + iq) * HD;
            #pragma unroll
            for (int ch = 0; ch < 4; ch++)
                *(float4*)&Qs[iq * QSTR + lc + ch * 32] =
                    *(const float4*)&src[lc + ch * 32];
        }

        float O[4][8] = {};
        float m[4], l[4];
        #pragma unroll
        for (int rr = 0; rr < 4; rr++) { m[rr] = -1e30f; l[rr] = 0.f; }

        float4 kpref[4];
        #pragma unroll
        for (int ch = 0; ch < 4; ch++)
            kpref[ch] = *(const float4*)&kbase[(size_t)lr * HD + lc + ch * 32];

        __syncthreads();

        for (int kt = 0; kt < ntiles; kt++) {
            const int k0 = kt * ABK;

            #pragma unroll
            for (int ch = 0; ch < 4; ch++)
                *(float4*)&KV[lr * KVSTR + lc + ch * 32] = kpref[ch];
            __syncthreads();

            float4 vpref[4];
            #pragma unroll
            for (int ch = 0; ch < 4; ch++)
                vpref[ch] = *(const float4*)&vbase[(size_t)(k0 + lr) * HD + lc + ch * 32];

            float acc[4][2] = {};
            #pragma unroll 4
            for (int d0 = 0; d0 < HD; d0 += 4) {
                float4 ka = *(const float4*)&KV[(j0 + 0) * KVSTR + d0];
                float4 kb4 = *(const float4*)&KV[(j0 + 1) * KVSTR + d0];
                #pragma unroll
                for (int rr = 0; rr < 4; rr++) {
                    float4 q4 = *(const float4*)&Qs[(i0 + rr) * QSTR + d0];
                    acc[rr][0] += q4.x * ka.x + q4.y * ka.y + q4.z * ka.z + q4.w * ka.w;
                    acc[rr][1] += q4.x * kb4.x + q4.y * kb4.y + q4.z * kb4.z + q4.w * kb4.w;
                }
            }

            const bool need_mask = (k0 + ABK - 1) > q0;
            float p[4][2], alpha[4];
            #pragma unroll
            for (int rr = 0; rr < 4; rr++) {
                float z0 = acc[rr][0] * kSc;
                float z1 = acc[rr][1] * kSc;
                if (need_mask) {
                    if (k0 + j0 + 0 > q0 + i0 + rr) z0 = -1e30f;
                    if (k0 + j0 + 1 > q0 + i0 + rr) z1 = -1e30f;
                }
                float rmax = fmaxf(z0, z1);
                #pragma unroll
                for (int off = 1; off < 16; off <<= 1)
                    rmax = fmaxf(rmax, __shfl_xor(rmax, off, 16));
                const float nm = fmaxf(m[rr], rmax);
                alpha[rr] = exp2f(m[rr] - nm);
                p[rr][0] = exp2f(z0 - nm);
                p[rr][1] = exp2f(z1 - nm);
                float ts = p[rr][0] + p[rr][1];
                #pragma unroll
                for (int off = 1; off < 16; off <<= 1)
                    ts += __shfl_xor(ts, off, 16);
                l[rr] = l[rr] * alpha[rr] + ts;
                m[rr] = nm;
            }
            __syncthreads();

            #pragma unroll
            for (int ch = 0; ch < 4; ch++)
                *(float4*)&KV[lr * KVSTR + lc + ch * 32] = vpref[ch];
            *(float4*)&Psf[(j0 + 0) * PSTR + i0] =
                make_float4(p[0][0], p[1][0], p[2][0], p[3][0]);
            *(float4*)&Psf[(j0 + 1) * PSTR + i0] =
                make_float4(p[0][1], p[1][1], p[2][1], p[3][1]);
            if (kt + 1 < ntiles) {
                #pragma unroll
                for (int ch = 0; ch < 4; ch++)
                    kpref[ch] = *(const float4*)&kbase[(size_t)(k0 + ABK + lr) * HD + lc + ch * 32];
            }
            __syncthreads();

            #pragma unroll
            for (int rr = 0; rr < 4; rr++)
                #pragma unroll
                for (int c = 0; c < 8; c++)
                    O[rr][c] *= alpha[rr];
            #pragma unroll 4
            for (int j = 0; j < ABK; j++) {
                float4 pj = *(const float4*)&Psf[j * PSTR + i0];
                float4 v0 = *(const float4*)&KV[j * KVSTR + dd0];
                float4 v1 = *(const float4*)&KV[j * KVSTR + dd0 + 4];
                const float pr[4] = {pj.x, pj.y, pj.z, pj.w};
                const float vv[8] = {v0.x, v0.y, v0.z, v0.w, v1.x, v1.y, v1.z, v1.w};
                #pragma unroll
                for (int rr = 0; rr < 4; rr++)
                    #pragma unroll
                    for (int c = 0; c < 8; c++)
                        O[rr][c] += pr[rr] * vv[c];
            }
            __syncthreads();
        }

        #pragma unroll
        for (int rr = 0; rr < 4; rr++) {
            const float inv = 1.0f / l[rr];
            const int qg = q0 + i0 + rr;
            float4 o0 = make_float4(O[rr][0] * inv, O[rr][1] * inv,
                                    O[rr][2] * inv, O[rr][3] * inv);
            float4 o1 = make_float4(O[rr][4] * inv, O[rr][5] * inv,
                                    O[rr][6] * inv, O[rr][7] * inv);
            float* dst = &ctx[((size_t)qg * H + h) * HD + dd0];
            *(float4*)&dst[0] = o0;
            *(float4*)&dst[4] = o1;
        }
        __syncthreads();
    }
}

__global__ __launch_bounds__(256) void gemm_dense_kernel(
    const float* __restrict__ A, const float* __restrict__ W,
    const float* __restrict__ bias, float* __restrict__ out)
{
    __shared__ float As[16][68];
    __shared__ float Bs[16][64];
    const int bx = blockIdx.x;
    const int by = blockIdx.y;
    const int tid = threadIdx.x;
    const int tx = tid & 15, ty = tid >> 4;
    const int row0 = by * 64, col0 = bx * 64;
    const int am = tid >> 2;
    const int ak = (tid & 3) * 4;
    const int bk = tid >> 4;
    const int bn = (tid & 15) * 4;
    float acc[4][4] = {};
    for (int k0 = 0; k0 < D; k0 += 16) {
        float4 av = *(const float4*)&A[(size_t)(row0 + am) * D + k0 + ak];
        float4 bv = *(const float4*)&W[(size_t)(k0 + bk) * D + col0 + bn];
        __syncthreads();
        As[ak + 0][am] = av.x; As[ak + 1][am] = av.y;
        As[ak + 2][am] = av.z; As[ak + 3][am] = av.w;
        *(float4*)&Bs[bk][bn] = bv;
        __syncthreads();
        #pragma unroll
        for (int k = 0; k < 16; k++) {
            float4 a4 = *(const float4*)&As[k][ty * 4];
            float4 b4 = *(const float4*)&Bs[k][tx * 4];
            float a[4] = {a4.x, a4.y, a4.z, a4.w};
            float b[4] = {b4.x, b4.y, b4.z, b4.w};
            #pragma unroll
            for (int r = 0; r < 4; r++)
                #pragma unroll
                for (int c = 0; c < 4; c++)
                    acc[r][c] += a[r] * b[c];
        }
    }
    const int j0 = col0 + tx * 4;
    const float bv0 = bias[j0 + 0], bv1 = bias[j0 + 1];
    const float bv2 = bias[j0 + 2], bv3 = bias[j0 + 3];
    #pragma unroll
    for (int r = 0; r < 4; r++) {
        const int grow = row0 + ty * 4 + r;
        float4 o4 = make_float4(acc[r][0] + bv0, acc[r][1] + bv1,
                                acc[r][2] + bv2, acc[r][3] + bv3);
        *(float4*)&out[(size_t)grow * D + j0] = o4;
    }
}

extern "C" void kernel_launch(void* const* d_in, const int* in_sizes, int n_in,
                              void* d_out, int out_size, void* d_ws, size_t ws_size,
                              hipStream_t stream) {
    const float* x      = (const float*)d_in[0];
    const float* freqs  = (const float*)d_in[1];
    const int*   pos    = (const int*)d_in[2];
    const float* Wqkv   = (const float*)d_in[3];
    const float* bqkv   = (const float*)d_in[4];
    const float* Wdense = (const float*)d_in[5];
    const float* bdense = (const float*)d_in[6];
    float* out = (float*)d_out;

    const size_t nSD = (size_t)S * D;   // 4 Mi elems
    const size_t nW1 = (size_t)D * N3;  // 12 Mi elems
    const size_t nOP = (size_t)1024 * 64 * 128;   // split-K partial O (f32)
    const size_t nML = (size_t)1024 * 128;        // split-K partial m,l (f32)

    const size_t needed =
        (6 * nSD + nW1) * sizeof(ushort_t) + (nOP + nML) * sizeof(float);

    if (ws_size >= needed) {
        ushort_t* qh   = (ushort_t*)d_ws;
        ushort_t* kh   = qh + nSD;
        ushort_t* vh   = kh + nSD;
        ushort_t* ctxh = vh + nSD;
        ushort_t* xh   = ctxh + nSD;
        ushort_t* Wth  = xh + nSD;
        ushort_t* Wdth = Wth + nW1;
        float* Opart = (float*)(Wdth + nSD);
        float* MLpart = Opart + nOP;

        convert_f16_kernel<<<nSD / 4 / 256, 256, 0, stream>>>(x, xh);
        dim3 gt1(D / 32, N3 / 32);
        convert_t_kernel<<<gt1, 256, 0, stream>>>(Wqkv, Wth, D, N3);
        dim3 gt2(D / 32, D / 32);
        convert_t_kernel<<<gt2, 256, 0, stream>>>(Wdense, Wdth, D, D);

        dim3 g1(N3 / 256, S / 256);   // 24 x 8 = 192 blocks, 512 thr
        gemm_qkv_mfma<<<g1, 512, 0, stream>>>(xh, Wth, bqkv, freqs,
                                              pos, qh, kh, vh);
        attn_mfma_kernel<<<1024, 256, 0, stream>>>(qh, kh, vh,
                                                   Opart, MLpart);
        dim3 gc(32, H);
        attn_combine_kernel<<<gc, 128, 0, stream>>>(Opart, MLpart, ctxh);
        dim3 g3(D / 128, S / 128);
        gemm_dense_mfma<<<g3, 256, 0, stream>>>(ctxh, Wdth, bdense, out);
    } else {
        // fallback: R2 f32 path (needs only 64 MiB)
        float* qb  = (float*)d_ws;
        float* kb  = qb + (size_t)H * S * HD;
        float* vb  = kb + (size_t)H * S * HD;
        float* ctx = vb + (size_t)H * S * HD;
        dim3 g1(N3 / 64, S / 64);
        gemm_qkv_kernel<<<g1, 256, 0, stream>>>(x, Wqkv, bqkv, freqs, pos, qb, kb, vb);
        dim3 g2(16, H);
        attn_kernel<<<g2, 256, 0, stream>>>(qb, kb, vb, ctx);
        dim3 g3(D / 64, S / 64);
        gemm_dense_kernel<<<g3, 256, 0, stream>>>(ctx, Wdense, bdense, out);
    }
}

// Round 3
// 340.672 us; speedup vs baseline: 1.3692x; 1.0414x over previous
//
#include <hip/hip_runtime.h>

#define S 2048
#define D 2048
#define H 16
#define HD 128
#define N3 6144  // 3*D

typedef __attribute__((ext_vector_type(8))) _Float16 f16x8;
typedef __attribute__((ext_vector_type(4))) float f32x4;
typedef unsigned short ushort_t;
typedef unsigned int uint_t;

// ---------------------------------------------------------------------------
// f16 helpers (v_cvt_f16_f32 is RNE)
// ---------------------------------------------------------------------------
__device__ __forceinline__ ushort_t f16_rne(float f) {
    _Float16 h = (_Float16)f;
    return __builtin_bit_cast(ushort_t, h);
}
__device__ __forceinline__ float f16_f32(ushort_t u) {
    return (float)__builtin_bit_cast(_Float16, u);
}

// f32 row-major -> f16 (activations)
__global__ __launch_bounds__(256) void convert_f16_kernel(
    const float* __restrict__ in, ushort_t* __restrict__ hi)
{
    const int i = blockIdx.x * 256 + threadIdx.x;  // per float4
    float4 v = ((const float4*)in)[i];
    ((ushort4*)hi)[i] = make_ushort4(f16_rne(v.x), f16_rne(v.y),
                                     f16_rne(v.z), f16_rne(v.w));
}

// W [K][N] f32 -> Wt [N][K] f16 (transpose + convert), 32x32 tiles.
__global__ __launch_bounds__(256) void convert_t_kernel(
    const float* __restrict__ in, ushort_t* __restrict__ hi,
    int Kdim, int Ndim)
{
    __shared__ float tile[32][33];
    const int k0 = blockIdx.x * 32, n0 = blockIdx.y * 32;
    const int tx = threadIdx.x & 31, ty = threadIdx.x >> 5;  // ty 0..7
    #pragma unroll
    for (int r = 0; r < 4; r++)
        tile[ty + r * 8][tx] = in[(size_t)(k0 + ty + r * 8) * Ndim + n0 + tx];
    __syncthreads();
    const int n  = threadIdx.x >> 3;        // 0..31 local col
    const int kc = (threadIdx.x & 7) * 4;   // 0..28 local k chunk
    const float v0 = tile[kc + 0][n], v1 = tile[kc + 1][n];
    const float v2 = tile[kc + 2][n], v3 = tile[kc + 3][n];
    const size_t off = (size_t)(n0 + n) * Kdim + k0 + kc;
    *(ushort4*)&hi[off] = make_ushort4(f16_rne(v0), f16_rne(v1),
                                       f16_rne(v2), f16_rne(v3));
}

// ---------------------------------------------------------------------------
// async global->LDS, 16 B per lane, wave-uniform LDS base (HW adds lane*16).
// ---------------------------------------------------------------------------
__device__ __forceinline__ void gload16(const ushort_t* g, ushort_t* l) {
    __builtin_amdgcn_global_load_lds(
        (const __attribute__((address_space(1))) unsigned int*)g,
        (__attribute__((address_space(3))) unsigned int*)l, 16, 0, 0);
}

__device__ __forceinline__ void vwait8() { asm volatile("s_waitcnt vmcnt(8)" ::: "memory"); }
__device__ __forceinline__ void vwait4() { asm volatile("s_waitcnt vmcnt(4)" ::: "memory"); }
__device__ __forceinline__ void vwait0() { asm volatile("s_waitcnt vmcnt(0)" ::: "memory"); }
__device__ __forceinline__ void lwait0() { asm volatile("s_waitcnt lgkmcnt(0)" ::: "memory"); }

// ---------------------------------------------------------------------------
// R15: 128x128 / BK=64 / 4-wave / 2-phase-per-tile counted-vmcnt core.
// R2 post-mortem: 256^2 8-phase = 192 blocks (<256 CUs) + 128KB LDS
// (1 block/CU) -> every barrier fully exposed. This core: 64 KB LDS ->
// 2 blocks/CU; grid 768 (qkv) fills all CUs; cross-block asynchrony hides
// each block's barrier/lgkm drains.
// LDS layout per buffer (T&1): j0=A.k0 j1=B.k0 j2=A.k1 j3=B.k1, each
// 128 rows x 32 k f16 (8 KB, 64 B row stride -> frag ds_read_b128 is a
// contiguous 1KB/wave = conflict-free; staging dest linear = gload_lds ok).
// Schedule per tile T (phases kk=0,1):
//   ph0: read frags(kk0); stage j2,j3 of T+1; bar; lgkm0; 16 MFMA; vmcnt(8); bar
//   ph1: read frags(kk1); stage j0,j1 of T+2; bar; lgkm0; 16 MFMA; vmcnt(8); bar
// Region lifetime: stage(T+1,j2/j3) in ph0 writes buf (T+1)&1 whose j2/j3
// was last read in T-1 ph1 (completed pre-barrier) -> safe. stage(T+2,j0/j1)
// in ph1 writes CURRENT buf j0/j1, last read in ph0 (complete before ph0's
// end barrier; store issued after) -> safe. vmcnt(8) at each phase end
// completes exactly the 4 loads (2 regions) the NEXT phase reads.
// Tail: T=QNT-2 ph1 no stage + vmcnt(4); T=QNT-1 ph0 vmcnt(0), ph1 none.
// ---------------------------------------------------------------------------
#define QNT 32   // D / 64 K-tiles

__device__ __forceinline__ void mm_core_8ph(
    const ushort_t* __restrict__ At, const ushort_t* __restrict__ Bt,
    ushort_t* lds, const int t, f32x4 (&acc)[4][4])
{
    const int w = t >> 6, lane = t & 63;
    const int lr = lane & 15, quad = lane >> 4;
    const int wm = (w & 1) * 64;
    const int wn = (w >> 1) * 64;

    const int srow = lane >> 2;          // 0..15
    const int scol = (lane & 3) * 8;     // 16B chunk
    const size_t goff0 = (size_t)(w * 16 + srow) * D + scol;   // rows 0..63
    const size_t goff1 = goff0 + (size_t)64 * D;               // rows 64..127
    const int ldst0 = w * 512;
    const int ldst1 = 2048 + w * 512;

    auto stage = [&](int j, int Tt) {
        const ushort_t* gb = (j & 1) ? Bt : At;
        const size_t off = (size_t)Tt * 64 + (j >> 1) * 32;
        ushort_t* dst = lds + (Tt & 1) * 16384 + j * 4096;
        gload16(gb + goff0 + off, dst + ldst0);
        gload16(gb + goff1 + off, dst + ldst1);
    };

    const int aro = (wm + lr) * 32 + quad * 8;
    const int bro = 4096 + (wn + lr) * 32 + quad * 8;

    // prologue: tile0 all 4 regions + tile1 j0,j1; wait tile0 complete
    stage(0, 0); stage(1, 0); stage(2, 0); stage(3, 0);
    stage(0, 1); stage(1, 1);
    vwait4();
    __builtin_amdgcn_sched_barrier(0);
    __builtin_amdgcn_s_barrier();

    f16x8 af[4], bf[4];

#define PH(kk, DOSTAGE, ST, WAITN)                                         \
    {                                                                      \
        const ushort_t* base = lds + (T & 1) * 16384 + (kk) * 8192;        \
        _Pragma("unroll")                                                  \
        for (int i = 0; i < 4; i++)                                        \
            af[i] = *(const f16x8*)&base[aro + i * 512];                   \
        _Pragma("unroll")                                                  \
        for (int n = 0; n < 4; n++)                                        \
            bf[n] = *(const f16x8*)&base[bro + n * 512];                   \
        if (DOSTAGE) {                                                     \
            stage((kk) ? 0 : 2, ST);                                       \
            stage((kk) ? 1 : 3, ST);                                       \
        }                                                                  \
        __builtin_amdgcn_s_barrier();                                      \
        lwait0();                                                          \
        __builtin_amdgcn_sched_barrier(0);                                 \
        __builtin_amdgcn_s_setprio(1);                                     \
        _Pragma("unroll")                                                  \
        for (int i = 0; i < 4; i++)                                        \
            _Pragma("unroll")                                              \
            for (int n = 0; n < 4; n++)                                    \
                acc[i][n] = __builtin_amdgcn_mfma_f32_16x16x32_f16(        \
                    af[i], bf[n], acc[i][n], 0, 0, 0);                     \
        __builtin_amdgcn_s_setprio(0);                                     \
        WAITN;                                                             \
        __builtin_amdgcn_s_barrier();                                      \
    }

    for (int T = 0; T < QNT - 2; T++) {
        PH(0, true, T + 1, vwait8());
        PH(1, true, T + 2, vwait8());
    }
    {
        const int T = QNT - 2;
        PH(0, true,  T + 1, vwait8());
        PH(1, false, 0,     vwait4());
    }
    {
        const int T = QNT - 1;
        PH(0, false, 0, vwait0());
        PH(1, false, 0, );
    }
#undef PH
}

// ---------------------------------------------------------------------------
// QKV GEMM (f16 1-term, 8-phase core). q/k/v all stored f16.
// ---------------------------------------------------------------------------
__global__ __launch_bounds__(256, 2) void gemm_qkv_mfma(
    const ushort_t* __restrict__ xh,
    const ushort_t* __restrict__ Wth,
    const float* __restrict__ bias, const float* __restrict__ freqs,
    const int* __restrict__ input_pos,
    ushort_t* __restrict__ qhg, ushort_t* __restrict__ khg,
    ushort_t* __restrict__ vhg)
{
    __shared__ ushort_t lds[32768];   // 64 KB
    const int t = threadIdx.x;
    const int col0 = blockIdx.x * 128;
    const int row0 = blockIdx.y * 128;

    f32x4 acc[4][4] = {};
    mm_core_8ph(xh + (size_t)row0 * D, Wth + (size_t)col0 * D, lds, t, acc);

    const int lane = t & 63;
    const int quad = lane >> 4;
    const int lr   = lane & 15;
    const int w = t >> 6;
    const int wm = (w & 1) * 64;
    const int wn = (w >> 1) * 64;

    const int which = col0 >> 11;           // 0=q 1=k 2=v (128 | 2048)
    const int hh = (col0 & 2047) >> 7;

    if (which == 2) {
        ushort_t* vh_b = vhg + (size_t)hh * HD * S;
        #pragma unroll
        for (int nt = 0; nt < 4; nt++) {
            const int d = wn + nt * 16 + lr;
            const float bsc = bias[col0 + d];
            #pragma unroll
            for (int mt = 0; mt < 4; mt++) {
                #pragma unroll
                for (int reg = 0; reg < 4; reg++) {
                    const int m = row0 + wm + mt * 16 + quad * 4 + reg;
                    const float v = acc[mt][nt][reg] + bsc;
                    vh_b[(size_t)d * S + input_pos[m]] = f16_rne(v);
                }
            }
        }
    } else {
        ushort_t* oh_b = ((which == 0) ? qhg : khg) + (size_t)hh * S * HD;
        #pragma unroll
        for (int nt = 0; nt < 4; nt++) {
            const int d = wn + nt * 16 + lr;
            const float bsc = bias[col0 + d];
            #pragma unroll
            for (int mt = 0; mt < 4; mt++) {
                #pragma unroll
                for (int reg = 0; reg < 4; reg++) {
                    const int m = row0 + wm + mt * 16 + quad * 4 + reg;
                    const float v = acc[mt][nt][reg] + bsc;
                    const float* fc = &freqs[((size_t)m * 64 + (d >> 1)) * 2];
                    const float cc = fc[0], ss = fc[1];
                    const float p = __shfl_xor(v, 1);
                    const float o = (d & 1) ? (v * cc + p * ss) : (v * cc - p * ss);
                    const ushort_t hv = f16_rne(o);
                    const int hp = __shfl_xor((int)hv, 1);
                    if (!(d & 1)) {
                        const int srowg = (which == 0) ? m : input_pos[m];
                        *(uint_t*)&oh_b[(size_t)srowg * HD + d] =
                            (uint_t)hv | ((uint_t)hp << 16);
                    }
                }
            }
        }
    }
}

// ---------------------------------------------------------------------------
// Dense GEMM (f16 1-term, 8-phase core): out = ctx @ Wd + b
// ---------------------------------------------------------------------------
__global__ __launch_bounds__(256, 2) void gemm_dense_mfma(
    const ushort_t* __restrict__ Ah,
    const ushort_t* __restrict__ Wth,
    const float* __restrict__ bias, float* __restrict__ out)
{
    __shared__ ushort_t lds[32768];   // 64 KB
    const int t = threadIdx.x;
    const int col0 = blockIdx.x * 128;
    const int row0 = blockIdx.y * 128;

    f32x4 acc[4][4] = {};
    mm_core_8ph(Ah + (size_t)row0 * D, Wth + (size_t)col0 * D, lds, t, acc);

    const int lane = t & 63;
    const int quad = lane >> 4;
    const int lr   = lane & 15;
    const int w = t >> 6;
    const int wm = (w & 1) * 64;
    const int wn = (w >> 1) * 64;

    #pragma unroll
    for (int nt = 0; nt < 4; nt++) {
        const int n = col0 + wn + nt * 16 + lr;
        const float bsc = bias[n];
        #pragma unroll
        for (int mt = 0; mt < 4; mt++) {
            #pragma unroll
            for (int reg = 0; reg < 4; reg++) {
                const int m = row0 + wm + mt * 16 + quad * 4 + reg;
                const float o = acc[mt][nt][reg] + bsc;
                const float po = __shfl_xor(o, 1);
                if (!(n & 1))
                    *(float2*)&out[(size_t)m * D + n] = make_float2(o, po);
            }
        }
    }
}

// ---------------------------------------------------------------------------
// MFMA flash attention, SPLIT-K x2 (flash-decoding). 1024 blocks:
// bi -> h = (bi&7)+8*((bi>>3)&1) (XCD locality), half=(bi>>4)&1, qi=bi>>5,
// r = (h&8)? qi : 31-qi (pairwise CU balance). Partial (unnorm O, m, l) ->
// ws; exact online-softmax merge in attn_combine_kernel. All-f16, PV 1-term.
// ---------------------------------------------------------------------------
__global__ __launch_bounds__(256, 2) void attn_mfma_kernel(
    const ushort_t* __restrict__ qhg, const ushort_t* __restrict__ khg,
    const ushort_t* __restrict__ vhg,
    float* __restrict__ Opart, float* __restrict__ MLpart)
{
    __shared__ ushort_t Khs[2][4096];   // [buf][hf*512.. key*32 + d8] per wave chunk
    __shared__ ushort_t Vhs[2][4096];   // [buf][dim*32 + key8]
    __shared__ ushort_t Ps[64 * 32];

    const int bi   = blockIdx.x;           // 0..1023
    const int h    = (bi & 7) + 8 * ((bi >> 3) & 1);
    const int half = (bi >> 4) & 1;
    const int qi   = bi >> 5;              // 0..31
    const int r = (h & 8) ? qi : (31 - qi);
    const int q0 = r * 64;
    const int nhalf = r + 1;
    const int kt0 = half * nhalf;
    const int kt1 = kt0 + nhalf;
    const int t = threadIdx.x;
    const int w = t >> 6, lane = t & 63;
    const int lr = lane & 15, quad = lane >> 4;

    const size_t qrow = (size_t)h * S + q0 + w * 16 + lr;
    f16x8 qf[4];
    #pragma unroll
    for (int ks = 0; ks < 4; ks++)
        qf[ks] = *(const f16x8*)&qhg[qrow * HD + ks * 32 + quad * 8];

    const ushort_t* kh_b = khg + (size_t)h * S * HD;
    const ushort_t* vh_b = vhg + (size_t)h * HD * S;

    const int keyq = lane >> 2;   // 0..15
    const int sub  = lane & 3;    // 16B chunk index

    auto stage = [&](int kt, int buf) {
        const int k0 = kt * 32;
        #pragma unroll
        for (int hf = 0; hf < 2; hf++) {
            const size_t ksrc = (size_t)(k0 + hf * 16 + keyq) * HD + w * 32 + sub * 8;
            gload16(kh_b + ksrc, &Khs[buf][w * 1024 + hf * 512]);
            const int dim = w * 32 + hf * 16 + keyq;
            const size_t vsrc = (size_t)dim * S + k0 + sub * 8;
            gload16(vh_b + vsrc, &Vhs[buf][(w * 32 + hf * 16) * 32]);
        }
    };

    f32x4 O[8] = {};
    f32x4 Ol = {0.f, 0.f, 0.f, 0.f};   // ones-column: per-row denom (unnorm)
    float mrow[4];
    #pragma unroll
    for (int rr = 0; rr < 4; rr++) mrow[rr] = -1e30f;

    f16x8 onesv;
    #pragma unroll
    for (int i = 0; i < 8; i++) onesv[i] = (_Float16)1.0f;

    const float kSc = 0.08838834764831845f * 1.4426950408889634f; // scale*log2e

    stage(kt0, 0);

    for (int kt = kt0; kt < kt1; kt++) {
        const int k0 = kt * 32;
        const int cur = (kt - kt0) & 1;
        __syncthreads();  // drains vmcnt -> tile kt visible; buf cur^1 free

        if (kt + 1 < kt1) stage(kt + 1, cur ^ 1);

        // ---- scores (f16 q*k, f32 accum)
        f32x4 sa[2];
        #pragma unroll
        for (int nt = 0; nt < 2; nt++) {
            f32x4 s = {0.f, 0.f, 0.f, 0.f};
            #pragma unroll
            for (int ks = 0; ks < 4; ks++) {
                f16x8 kf = *(const f16x8*)&Khs[cur][ks * 1024 + (nt * 16 + lr) * 32 + quad * 8];
                s = __builtin_amdgcn_mfma_f32_16x16x32_f16(qf[ks], kf, s, 0, 0, 0);
            }
            sa[nt] = s;
        }

        const int rowbase = q0 + w * 16 + quad * 4;
        const bool need_mask = (k0 + 31) > (q0 + w * 16);
        float alpha[4], pv0[4], pv1[4];
        #pragma unroll
        for (int rr = 0; rr < 4; rr++) {
            float z0 = sa[0][rr] * kSc;
            float z1 = sa[1][rr] * kSc;
            if (need_mask) {
                const int rowg = rowbase + rr;
                if (k0 + lr > rowg)      z0 = -1e30f;
                if (k0 + 16 + lr > rowg) z1 = -1e30f;
            }
            float rm = fmaxf(z0, z1);
            #pragma unroll
            for (int off = 1; off < 16; off <<= 1)
                rm = fmaxf(rm, __shfl_xor(rm, off));
            const float nm = fmaxf(mrow[rr], rm);
            alpha[rr] = exp2f(mrow[rr] - nm);
            pv0[rr] = exp2f(z0 - nm);
            pv1[rr] = exp2f(z1 - nm);
            mrow[rr] = nm;
        }

        #pragma unroll
        for (int rr = 0; rr < 4; rr++) {
            const int prow = (w * 16 + quad * 4 + rr) * 32;
            Ps[prow + lr]      = f16_rne(pv0[rr]);
            Ps[prow + 16 + lr] = f16_rne(pv1[rr]);
        }
        // no barrier: each wave reads only its own P rows (lgkmcnt orders)

        #pragma unroll
        for (int nt = 0; nt < 8; nt++)
            #pragma unroll
            for (int rr = 0; rr < 4; rr++)
                O[nt][rr] *= alpha[rr];
        #pragma unroll
        for (int rr = 0; rr < 4; rr++)
            Ol[rr] *= alpha[rr];
        const f16x8 pf = *(const f16x8*)&Ps[(w * 16 + lr) * 32 + quad * 8];
        #pragma unroll
        for (int nt = 0; nt < 8; nt++) {
            f16x8 vf = *(const f16x8*)&Vhs[cur][(nt * 16 + lr) * 32 + quad * 8];
            O[nt] = __builtin_amdgcn_mfma_f32_16x16x32_f16(pf, vf, O[nt], 0, 0, 0);
        }
        Ol = __builtin_amdgcn_mfma_f32_16x16x32_f16(pf, onesv, Ol, 0, 0, 0);
    }

    // ---- store unnormalized partial O + (m, l) for the combine pass
    float* Ob = Opart + (size_t)bi * 64 * 128;
    #pragma unroll
    for (int rr = 0; rr < 4; rr++) {
        const int row = w * 16 + quad * 4 + rr;
        #pragma unroll
        for (int nt = 0; nt < 8; nt++)
            Ob[(size_t)row * 128 + nt * 16 + lr] = O[nt][rr];
        if (lr == 0) {
            MLpart[(size_t)bi * 128 + row * 2 + 0] = mrow[rr];
            MLpart[(size_t)bi * 128 + row * 2 + 1] = Ol[rr];
        }
    }
}

// ---------------------------------------------------------------------------
// Exact online-softmax merge of the two split-K halves -> ctxh (f16).
// ---------------------------------------------------------------------------
__global__ __launch_bounds__(128) void attn_combine_kernel(
    const float* __restrict__ Opart, const float* __restrict__ MLpart,
    ushort_t* __restrict__ ctxh)
{
    const int qt = blockIdx.x;   // 0..31 (qi in attn kernel)
    const int h  = blockIdx.y;   // 0..15
    const int t  = threadIdx.x;  // 0..127
    const int b0 = h | (qt << 5);          // half 0
    const int b1 = b0 | (1 << 4);          // half 1
    const int r = (h & 8) ? qt : (31 - qt);
    const int q0 = r * 64;

    __shared__ float sc[64][2];
    if (t < 64) {
        const float m0 = MLpart[(size_t)b0 * 128 + t * 2 + 0];
        const float l0 = MLpart[(size_t)b0 * 128 + t * 2 + 1];
        const float m1 = MLpart[(size_t)b1 * 128 + t * 2 + 0];
        const float l1 = MLpart[(size_t)b1 * 128 + t * 2 + 1];
        const float m = fmaxf(m0, m1);
        const float a0 = exp2f(m0 - m), a1 = exp2f(m1 - m);
        const float inv = 1.0f / (l0 * a0 + l1 * a1);
        sc[t][0] = a0 * inv;
        sc[t][1] = a1 * inv;
    }
    __syncthreads();

    const float* O0 = Opart + (size_t)b0 * 64 * 128;
    const float* O1 = Opart + (size_t)b1 * 64 * 128;
    for (int row = 0; row < 64; row++) {
        const float o = O0[(size_t)row * 128 + t] * sc[row][0] +
                        O1[(size_t)row * 128 + t] * sc[row][1];
        ctxh[(size_t)(q0 + row) * D + h * HD + t] = f16_rne(o);
    }
}

// ---------------------------------------------------------------------------
// Fallback f32 path (R2, known-good) for small workspace.
// ---------------------------------------------------------------------------
__global__ __launch_bounds__(256) void gemm_qkv_kernel(
    const float* __restrict__ x, const float* __restrict__ W,
    const float* __restrict__ bias, const float* __restrict__ freqs,
    const int* __restrict__ input_pos,
    float* __restrict__ qb, float* __restrict__ kb, float* __restrict__ vb)
{
    __shared__ float As[16][68];
    __shared__ float Bs[16][64];
    const int bx = blockIdx.x;
    const int by = blockIdx.y;
    const int tid = threadIdx.x;
    const int tx = tid & 15, ty = tid >> 4;
    const int row0 = by * 64, col0 = bx * 64;
    const int am = tid >> 2;
    const int ak = (tid & 3) * 4;
    const int bk = tid >> 4;
    const int bn = (tid & 15) * 4;
    float acc[4][4] = {};
    for (int k0 = 0; k0 < D; k0 += 16) {
        float4 av = *(const float4*)&x[(size_t)(row0 + am) * D + k0 + ak];
        float4 bv = *(const float4*)&W[(size_t)(k0 + bk) * N3 + col0 + bn];
        __syncthreads();
        As[ak + 0][am] = av.x; As[ak + 1][am] = av.y;
        As[ak + 2][am] = av.z; As[ak + 3][am] = av.w;
        *(float4*)&Bs[bk][bn] = bv;
        __syncthreads();
        #pragma unroll
        for (int k = 0; k < 16; k++) {
            float4 a4 = *(const float4*)&As[k][ty * 4];
            float4 b4 = *(const float4*)&Bs[k][tx * 4];
            float a[4] = {a4.x, a4.y, a4.z, a4.w};
            float b[4] = {b4.x, b4.y, b4.z, b4.w};
            #pragma unroll
            for (int r = 0; r < 4; r++)
                #pragma unroll
                for (int c = 0; c < 4; c++)
                    acc[r][c] += a[r] * b[c];
        }
    }
    const int j0 = col0 + tx * 4;
    const int which = j0 >> 11;
    const int hh = (j0 & 2047) >> 7;
    const int d0 = j0 & 127;
    const float bv0 = bias[j0 + 0], bv1 = bias[j0 + 1];
    const float bv2 = bias[j0 + 2], bv3 = bias[j0 + 3];
    #pragma unroll
    for (int r = 0; r < 4; r++) {
        const int grow = row0 + ty * 4 + r;
        float v0 = acc[r][0] + bv0, v1 = acc[r][1] + bv1;
        float v2 = acc[r][2] + bv2, v3 = acc[r][3] + bv3;
        if (which == 2) {
            const int pos = input_pos[grow];
            float4 o4 = make_float4(v0, v1, v2, v3);
            *(float4*)&vb[((size_t)hh * S + pos) * HD + d0] = o4;
        } else {
            const float* fc = &freqs[((size_t)grow * 64 + (d0 >> 1)) * 2];
            float c0 = fc[0], s0 = fc[1], c1 = fc[2], s1 = fc[3];
            float o0 = v0 * c0 - v1 * s0, o1 = v1 * c0 + v0 * s0;
            float o2 = v2 * c1 - v3 * s1, o3 = v3 * c1 + v2 * s1;
            float4 o4 = make_float4(o0, o1, o2, o3);
            if (which == 0) {
                *(float4*)&qb[((size_t)hh * S + grow) * HD + d0] = o4;
            } else {
                const int pos = input_pos[grow];
                *(float4*)&kb[((size_t)hh * S + pos) * HD + d0] = o4;
            }
        }
    }
}

#define BQ 64
#define ABK 32
#define QSTR 132
#define KVSTR 132
#define PSTR 68

__global__ __launch_bounds__(256) void attn_kernel(
    const float* __restrict__ qb, const float* __restrict__ kb,
    const float* __restrict__ vb, float* __restrict__ ctx)
{
    __shared__ float Qs[BQ * QSTR];
    __shared__ float KV[ABK * KVSTR];
    __shared__ float Psf[ABK * PSTR];

    const int pa = blockIdx.x;
    const int h  = blockIdx.y;
    const int t  = threadIdx.x;
    const int ty = t >> 4, tx = t & 15;
    const int i0  = ty * 4;
    const int j0  = tx * 2;
    const int dd0 = tx * 8;
    const int lr = t >> 3;
    const int lc = (t & 7) * 4;

    const float* kbase = kb + (size_t)h * S * HD;
    const float* vbase = vb + (size_t)h * S * HD;
    const float kSc = 0.08838834764831845f * 1.4426950408889634f;

    for (int ph = 0; ph < 2; ph++) {
        const int r = (ph == 0) ? pa : 31 - pa;
        const int q0 = r * BQ;
        const int ntiles = 2 * r + 2;

        #pragma unroll
        for (int pp = 0; pp < 2; pp++) {
            const int iq = lr + pp * 32;
            const float* src = qb + ((size_t)h * S + q0 + iq) * HD;
            #pragma unroll
            for (int ch = 0; ch < 4; ch++)
                *(float4*)&Qs[iq * QSTR + lc + ch * 32] =
                    *(const float4*)&src[lc + ch * 32];
        }

        float O[4][8] = {};
        float m[4], l[4];
        #pragma unroll
        for (int rr = 0; rr < 4; rr++) { m[rr] = -1e30f; l[rr] = 0.f; }

        float4 kpref[4];
        #pragma unroll
        for (int ch = 0; ch < 4; ch++)
            kpref[ch] = *(const float4*)&kbase[(size_t)lr * HD + lc + ch * 32];

        __syncthreads();

        for (int kt = 0; kt < ntiles; kt++) {
            const int k0 = kt * ABK;

            #pragma unroll
            for (int ch = 0; ch < 4; ch++)
                *(float4*)&KV[lr * KVSTR + lc + ch * 32] = kpref[ch];
            __syncthreads();

            float4 vpref[4];
            #pragma unroll
            for (int ch = 0; ch < 4; ch++)
                vpref[ch] = *(const float4*)&vbase[(size_t)(k0 + lr) * HD + lc + ch * 32];

            float acc[4][2] = {};
            #pragma unroll 4
            for (int d0 = 0; d0 < HD; d0 += 4) {
                float4 ka = *(const float4*)&KV[(j0 + 0) * KVSTR + d0];
                float4 kb4 = *(const float4*)&KV[(j0 + 1) * KVSTR + d0];
                #pragma unroll
                for (int rr = 0; rr < 4; rr++) {
                    float4 q4 = *(const float4*)&Qs[(i0 + rr) * QSTR + d0];
                    acc[rr][0] += q4.x * ka.x + q4.y * ka.y + q4.z * ka.z + q4.w * ka.w;
                    acc[rr][1] += q4.x * kb4.x + q4.y * kb4.y + q4.z * kb4.z + q4.w * kb4.w;
                }
            }

            const bool need_mask = (k0 + ABK - 1) > q0;
            float p[4][2], alpha[4];
            #pragma unroll
            for (int rr = 0; rr < 4; rr++) {
                float z0 = acc[rr][0] * kSc;
                float z1 = acc[rr][1] * kSc;
                if (need_mask) {
                    if (k0 + j0 + 0 > q0 + i0 + rr) z0 = -1e30f;
                    if (k0 + j0 + 1 > q0 + i0 + rr) z1 = -1e30f;
                }
                float rmax = fmaxf(z0, z1);
                #pragma unroll
                for (int off = 1; off < 16; off <<= 1)
                    rmax = fmaxf(rmax, __shfl_xor(rmax, off, 16));
                const float nm = fmaxf(m[rr], rmax);
                alpha[rr] = exp2f(m[rr] - nm);
                p[rr][0] = exp2f(z0 - nm);
                p[rr][1] = exp2f(z1 - nm);
                float ts = p[rr][0] + p[rr][1];
                #pragma unroll
                for (int off = 1; off < 16; off <<= 1)
                    ts += __shfl_xor(ts, off, 16);
                l[rr] = l[rr] * alpha[rr] + ts;
                m[rr] = nm;
            }
            __syncthreads();

            #pragma unroll
            for (int ch = 0; ch < 4; ch++)
                *(float4*)&KV[lr * KVSTR + lc + ch * 32] = vpref[ch];
            *(float4*)&Psf[(j0 + 0) * PSTR + i0] =
                make_float4(p[0][0], p[1][0], p[2][0], p[3][0]);
            *(float4*)&Psf[(j0 + 1) * PSTR + i0] =
                make_float4(p[0][1], p[1][1], p[2][1], p[3][1]);
            if (kt + 1 < ntiles) {
                #pragma unroll
                for (int ch = 0; ch < 4; ch++)
                    kpref[ch] = *(const float4*)&kbase[(size_t)(k0 + ABK + lr) * HD + lc + ch * 32];
            }
            __syncthreads();

            #pragma unroll
            for (int rr = 0; rr < 4; rr++)
                #pragma unroll
                for (int c = 0; c < 8; c++)
                    O[rr][c] *= alpha[rr];
            #pragma unroll 4
            for (int j = 0; j < ABK; j++) {
                float4 pj = *(const float4*)&Psf[j * PSTR + i0];
                float4 v0 = *(const float4*)&KV[j * KVSTR + dd0];
                float4 v1 = *(const float4*)&KV[j * KVSTR + dd0 + 4];
                const float pr[4] = {pj.x, pj.y, pj.z, pj.w};
                const float vv[8] = {v0.x, v0.y, v0.z, v0.w, v1.x, v1.y, v1.z, v1.w};
                #pragma unroll
                for (int rr = 0; rr < 4; rr++)
                    #pragma unroll
                    for (int c = 0; c < 8; c++)
                        O[rr][c] += pr[rr] * vv[c];
            }
            __syncthreads();
        }

        #pragma unroll
        for (int rr = 0; rr < 4; rr++) {
            const float inv = 1.0f / l[rr];
            const int qg = q0 + i0 + rr;
            float4 o0 = make_float4(O[rr][0] * inv, O[rr][1] * inv,
                                    O[rr][2] * inv, O[rr][3] * inv);
            float4 o1 = make_float4(O[rr][4] * inv, O[rr][5] * inv,
                                    O[rr][6] * inv, O[rr][7] * inv);
            float* dst = &ctx[((size_t)qg * H + h) * HD + dd0];
            *(float4*)&dst[0] = o0;
            *(float4*)&dst[4] = o1;
        }
        __syncthreads();
    }
}

__global__ __launch_bounds__(256) void gemm_dense_kernel(
    const float* __restrict__ A, const float* __restrict__ W,
    const float* __restrict__ bias, float* __restrict__ out)
{
    __shared__ float As[16][68];
    __shared__ float Bs[16][64];
    const int bx = blockIdx.x;
    const int by = blockIdx.y;
    const int tid = threadIdx.x;
    const int tx = tid & 15, ty = tid >> 4;
    const int row0 = by * 64, col0 = bx * 64;
    const int am = tid >> 2;
    const int ak = (tid & 3) * 4;
    const int bk = tid >> 4;
    const int bn = (tid & 15) * 4;
    float acc[4][4] = {};
    for (int k0 = 0; k0 < D; k0 += 16) {
        float4 av = *(const float4*)&A[(size_t)(row0 + am) * D + k0 + ak];
        float4 bv = *(const float4*)&W[(size_t)(k0 + bk) * D + col0 + bn];
        __syncthreads();
        As[ak + 0][am] = av.x; As[ak + 1][am] = av.y;
        As[ak + 2][am] = av.z; As[ak + 3][am] = av.w;
        *(float4*)&Bs[bk][bn] = bv;
        __syncthreads();
        #pragma unroll
        for (int k = 0; k < 16; k++) {
            float4 a4 = *(const float4*)&As[k][ty * 4];
            float4 b4 = *(const float4*)&Bs[k][tx * 4];
            float a[4] = {a4.x, a4.y, a4.z, a4.w};
            float b[4] = {b4.x, b4.y, b4.z, b4.w};
            #pragma unroll
            for (int r = 0; r < 4; r++)
                #pragma unroll
                for (int c = 0; c < 4; c++)
                    acc[r][c] += a[r] * b[c];
        }
    }
    const int j0 = col0 + tx * 4;
    const float bv0 = bias[j0 + 0], bv1 = bias[j0 + 1];
    const float bv2 = bias[j0 + 2], bv3 = bias[j0 + 3];
    #pragma unroll
    for (int r = 0; r < 4; r++) {
        const int grow = row0 + ty * 4 + r;
        float4 o4 = make_float4(acc[r][0] + bv0, acc[r][1] + bv1,
                                acc[r][2] + bv2, acc[r][3] + bv3);
        *(float4*)&out[(size_t)grow * D + j0] = o4;
    }
}

extern "C" void kernel_launch(void* const* d_in, const int* in_sizes, int n_in,
                              void* d_out, int out_size, void* d_ws, size_t ws_size,
                              hipStream_t stream) {
    const float* x      = (const float*)d_in[0];
    const float* freqs  = (const float*)d_in[1];
    const int*   pos    = (const int*)d_in[2];
    const float* Wqkv   = (const float*)d_in[3];
    const float* bqkv   = (const float*)d_in[4];
    const float* Wdense = (const float*)d_in[5];
    const float* bdense = (const float*)d_in[6];
    float* out = (float*)d_out;

    const size_t nSD = (size_t)S * D;   // 4 Mi elems
    const size_t nW1 = (size_t)D * N3;  // 12 Mi elems
    const size_t nOP = (size_t)1024 * 64 * 128;   // split-K partial O (f32)
    const size_t nML = (size_t)1024 * 128;        // split-K partial m,l (f32)

    const size_t needed =
        (6 * nSD + nW1) * sizeof(ushort_t) + (nOP + nML) * sizeof(float);

    if (ws_size >= needed) {
        ushort_t* qh   = (ushort_t*)d_ws;
        ushort_t* kh   = qh + nSD;
        ushort_t* vh   = kh + nSD;
        ushort_t* ctxh = vh + nSD;
        ushort_t* xh   = ctxh + nSD;
        ushort_t* Wth  = xh + nSD;
        ushort_t* Wdth = Wth + nW1;
        float* Opart = (float*)(Wdth + nSD);
        float* MLpart = Opart + nOP;

        convert_f16_kernel<<<nSD / 4 / 256, 256, 0, stream>>>(x, xh);
        dim3 gt1(D / 32, N3 / 32);
        convert_t_kernel<<<gt1, 256, 0, stream>>>(Wqkv, Wth, D, N3);
        dim3 gt2(D / 32, D / 32);
        convert_t_kernel<<<gt2, 256, 0, stream>>>(Wdense, Wdth, D, D);

        dim3 g1(N3 / 128, S / 128);   // 48 x 16 = 768 blocks, 256 thr
        gemm_qkv_mfma<<<g1, 256, 0, stream>>>(xh, Wth, bqkv, freqs,
                                              pos, qh, kh, vh);
        attn_mfma_kernel<<<1024, 256, 0, stream>>>(qh, kh, vh,
                                                   Opart, MLpart);
        dim3 gc(32, H);
        attn_combine_kernel<<<gc, 128, 0, stream>>>(Opart, MLpart, ctxh);
        dim3 g3(D / 128, S / 128);    // 16 x 16 = 256 blocks, 256 thr
        gemm_dense_mfma<<<g3, 256, 0, stream>>>(ctxh, Wdth, bdense, out);
    } else {
        // fallback: R2 f32 path (needs only 64 MiB)
        float* qb  = (float*)d_ws;
        float* kb  = qb + (size_t)H * S * HD;
        float* vb  = kb + (size_t)H * S * HD;
        float* ctx = vb + (size_t)H * S * HD;
        dim3 g1(N3 / 64, S / 64);
        gemm_qkv_kernel<<<g1, 256, 0, stream>>>(x, Wqkv, bqkv, freqs, pos, qb, kb, vb);
        dim3 g2(16, H);
        attn_kernel<<<g2, 256, 0, stream>>>(qb, kb, vb, ctx);
        dim3 g3(D / 64, S / 64);
        gemm_dense_kernel<<<g3, 256, 0, stream>>>(ctx, Wdense, bdense, out);
    }
}